// Round 17
// baseline (63703.967 us; speedup 1.0000x reference)
//
#include <hip/hip_runtime.h>
#include <hip/hip_cooperative_groups.h>
#include <math.h>
#include <stdint.h>
#include <limits.h>

#define VSZ 50257
#define ESZ 256
#define HSZ 1024
#define BSZ 64
#define TSZ 80
#define GC  4096            // 4*H gate columns
#define NFCB 786            // ceil(VSZ/64) FC col-blocks
#define NCAND (NFCB*5)      // 3930 candidates per batch row
#define NSLOT 13            // lstm part slots: A 0..8 (l0: 0..4, l1-rec: 5..8), B 9..12
#define NREF 16             // exact-refined candidates per batch row
#define MGRID 576           // megakernel grid (3 blocks/CU co-resident)

namespace cg = cooperative_groups;

typedef unsigned int u32;
typedef unsigned short u16;
typedef double f64x4 __attribute__((ext_vector_type(4)));
typedef float f32x4v __attribute__((ext_vector_type(4)));
typedef __bf16 bf16x8 __attribute__((ext_vector_type(8)));
union BFrag { u16 u[8]; bf16x8 v; };

__device__ __forceinline__ u16 f2bf(float f) {   // f32 -> bf16 RNE
  u32 x = __float_as_uint(f);
  return (u16)((x + 0x7FFFu + ((x >> 16) & 1u)) >> 16);
}
__device__ __forceinline__ float bf2f(u16 h) { return __uint_as_float(((u32)h) << 16); }

// ---------------- Threefry-2x32 (JAX exact) ----------------
__device__ __forceinline__ void tf2x32(u32 k0, u32 k1, u32& x0, u32& x1) {
  u32 ks2 = k0 ^ k1 ^ 0x1BD11BDAu;
  x0 += k0; x1 += k1;
#define RND(r) { x0 += x1; x1 = (x1 << r) | (x1 >> (32 - r)); x1 ^= x0; }
  RND(13) RND(15) RND(26) RND(6)
  x0 += k1; x1 += ks2 + 1u;
  RND(17) RND(29) RND(16) RND(24)
  x0 += ks2; x1 += k0 + 2u;
  RND(13) RND(15) RND(26) RND(6)
  x0 += k0; x1 += k1 + 3u;
  RND(17) RND(29) RND(16) RND(24)
  x0 += k1; x1 += ks2 + 4u;
  RND(13) RND(15) RND(26) RND(6)
  x0 += ks2; x1 += k0 + 5u;
#undef RND
}

__device__ __forceinline__ double dsig(double x) { return 0.5 + 0.5 * tanh(0.5 * x); }

// sorted-desc top5 insert; ties -> lower index first (matches lax.top_k)
__device__ __forceinline__ void ins5(double v, int i, double* tv, int* ti) {
  bool beat4 = (v > tv[4]) || (v == tv[4] && i < ti[4]);
  if (!beat4) return;
  tv[4] = v; ti[4] = i;
#pragma unroll
  for (int p = 4; p > 0; --p) {
    bool sw = (tv[p] > tv[p-1]) || (tv[p] == tv[p-1] && ti[p] < ti[p-1]);
    double a0 = sw ? tv[p] : tv[p-1]; double a1 = sw ? tv[p-1] : tv[p];
    tv[p-1] = a0; tv[p] = a1;
    int b0 = sw ? ti[p] : ti[p-1]; int b1 = sw ? ti[p-1] : ti[p];
    ti[p-1] = b0; ti[p] = b1;
  }
}

// exact integer reference D[m][n] for f64 probe: sum_k (4m+k+1)*(16k+n+1)
__device__ __forceinline__ double dref(int m, int n) {
  int s = 0;
#pragma unroll
  for (int k = 0; k < 4; ++k) s += (4*m + k + 1) * (16*k + n + 1);
  return (double)s;
}

// -------- MFMA layout probes: fb[0]=f64 conv (0..3), fb[2]=bf16 maps ok --------
__global__ __launch_bounds__(64) void k_probe(int* __restrict__ fbp) {
  int l = threadIdx.x;
  int lane16 = l & 15, sub = l >> 4;
  {
    double av = (double)(4 * lane16 + sub + 1);     // A[m=lane16][k=sub]
    double bv = (double)(16 * sub + lane16 + 1);    // B[k=sub][n=lane16]
    f64x4 acc = {0., 0., 0., 0.};
    acc = __builtin_amdgcn_mfma_f64_16x16x4f64(av, bv, acc, 0, 0, 0);
    bool o0 = true, o1 = true, o2 = true, o3 = true;
#pragma unroll
    for (int j = 0; j < 4; ++j) {
      double d = acc[j];
      o0 = o0 && (d == dref(4 * sub + j, lane16));
      o1 = o1 && (d == dref(lane16, 4 * sub + j));
      o2 = o2 && (d == dref(sub + 4 * j, lane16));
      o3 = o3 && (d == dref(lane16, sub + 4 * j));
    }
    int a0 = __all(o0), a1 = __all(o1), a2 = __all(o2), a3 = __all(o3);
    if (l == 0) { fbp[0] = a0 ? 0 : a1 ? 1 : a2 ? 2 : 3; fbp[1] = 0; }
  }
  {
    BFrag fa, fbv;
#pragma unroll
    for (int i = 0; i < 8; ++i) {
      int k = sub * 8 + i;
      fa.u[i]  = f2bf((float)((lane16 * 5 + k * 3) % 63 + 1));
      fbv.u[i] = f2bf((float)((k * 7 + lane16 * 11) % 61 + 1));
    }
    f32x4v c = {0.f, 0.f, 0.f, 0.f};
    c = __builtin_amdgcn_mfma_f32_16x16x32_bf16(fa.v, fbv.v, c, 0, 0, 0);
    bool okb = true;
#pragma unroll
    for (int j = 0; j < 4; ++j) {
      int mm = sub * 4 + j, nn = lane16;
      int ref = 0;
      for (int k = 0; k < 32; ++k) ref += ((mm*5 + k*3) % 63 + 1) * ((k*7 + nn*11) % 61 + 1);
      okb = okb && (c[j] == (float)ref);
    }
    int allb = __all(okb);
    if (l == 0) fbp[2] = allb;
  }
}

// -------- one-time: fc_w [k][v] f32 -> whT [v][k] bf16 (tiled transpose) --------
__global__ __launch_bounds__(256) void k_wconv(const float* __restrict__ W, u16* __restrict__ whT) {
  __shared__ u16 tile[64][65];
  int vb = blockIdx.x * 64, kb = blockIdx.y * 64;
  int tid = threadIdx.x;
#pragma unroll
  for (int i = 0; i < 16; ++i) {
    int r = i * 4 + (tid >> 6), c = tid & 63;
    int v = vb + c;
    tile[c][r] = (v < VSZ) ? f2bf(W[(size_t)(kb + r) * VSZ + v]) : (u16)0;
  }
  __syncthreads();
#pragma unroll
  for (int i = 0; i < 16; ++i) {
    int r = i * 4 + (tid >> 6), c = tid & 63;
    int v = vb + r;
    if (v < VSZ) whT[(size_t)v * 1024 + kb + c] = tile[r][c];
  }
}

// -------- fused RNG: gumbel[t][m] for t<80, m<320 --------
__global__ __launch_bounds__(256) void k_rng(double* __restrict__ gum) {
  int idx = blockIdx.x * 256 + threadIdx.x;
  if (idx >= TSZ * 320) return;
  int t = idx / 320, m = idx % 320;
  u32 a0 = 0u, a1 = (u32)t;
  tf2x32(0u, 42u, a0, a1);
  u32 x0 = 0u, x1 = (u32)m;
  tf2x32(a0, a1, x0, x1);
  u32 bits = x0 ^ x1;
  const float TINY = 1.17549435082228750797e-38f;  // 2^-126
  float f = __uint_as_float((bits >> 9) | 0x3f800000u) - 1.0f;
  float u = f + TINY;
  u = fmaxf(TINY, u);
  gum[idx] = -log(-log((double)u));
}

// -------- time encode stage 1 --------
__global__ __launch_bounds__(256) void k_time1(const float* __restrict__ hours, const float* __restrict__ w1,
                                               const float* __restrict__ bb1, double* __restrict__ tp1T) {
  int idx = blockIdx.x * 256 + threadIdx.x;
  int b = idx & 63, hcol = idx >> 6;
  const float TPO = (float)(2.0 * 3.14159265358979323846 / 24.0);
  float af = hours[b] * TPO;
  double a = (double)af;
  double sv = sin(a), cv = cos(a);
  double vv = tanh(sv * (double)w1[hcol] + cv * (double)w1[HSZ + hcol] + (double)bb1[hcol]);
  tp1T[(size_t)hcol * 64 + b] = vv;
}

// -------- simple split-K gemm (prologue-only, runs once) --------
__global__ __launch_bounds__(256) void k_gemm_simple(const double* __restrict__ XTa, const float* __restrict__ Wa,
                                                     int Ka, int Sa, double* __restrict__ part) {
  int j = blockIdx.x * 256 + threadIdx.x;
  if (j >= GC) return;
  int s = blockIdx.y;
  int kc = Ka / Sa, k0 = s * kc;
  double acc[BSZ];
#pragma unroll
  for (int b = 0; b < BSZ; ++b) acc[b] = 0.0;
  const float* wp = Wa + (size_t)k0 * GC + j;
  const double* xp = XTa + (size_t)k0 * 64;
  for (int k = 0; k < kc; ++k) {
    double wv = (double)wp[0]; wp += GC;
#pragma unroll
    for (int b = 0; b < BSZ; ++b) acc[b] = fma(wv, xp[b], acc[b]);
    xp += 64;
  }
  double* o = part + ((size_t)s * 64) * GC + j;
#pragma unroll
  for (int b = 0; b < BSZ; ++b) o[(size_t)b * GC] = acc[b];
}

// -------- time encode stage 2 reduce --------
__global__ __launch_bounds__(256) void k_t2r(const double* __restrict__ part, const float* __restrict__ b2,
                                             double* __restrict__ h0T, double* __restrict__ c0,
                                             double* __restrict__ h1T, double* __restrict__ c1) {
  int b = blockIdx.y;
  int j = blockIdx.x * 256 + threadIdx.x;
  double acc = (double)b2[j];
  for (int s = 0; s < 8; ++s) acc += part[((size_t)s * 64 + b) * GC + j];
  int l = j >> 11, half = (j >> 10) & 1, hcol = j & 1023;
  if (half == 0) (l ? h1T : h0T)[(size_t)hcol * 64 + b] = acc;
  else           (l ? c1 : c0)[(size_t)b * HSZ + hcol] = acc;
}

// ================= phase bodies (shared by megakernel and fallback kernels) =================

// LSTM MFMA unit: one 64-col block x one K=256 slice -> part slot
__device__ __forceinline__ void lstm_unit(int cb, int slot, const double* XT, const float* W, int k0,
                                          double* part, int conv, double* xs, int tid) {
  int l = tid & 63, wv = tid >> 6;
  int sub = l >> 4, lane16 = l & 15;
  int colbase = cb * 64;
  int colA = colbase + wv * 16 + lane16;
  f64x4 a0 = {0.,0.,0.,0.}, a1 = {0.,0.,0.,0.}, a2 = {0.,0.,0.,0.}, a3 = {0.,0.,0.,0.};
  const float* wp = W + (size_t)(k0 + sub) * GC + colA;
  float ab[8];
#pragma unroll
  for (int u = 0; u < 8; ++u) { ab[u] = wp[0]; wp += (size_t)4 * GC; }
  for (int ch = 0; ch < 4; ++ch) {
    __syncthreads();
    const double2* src = (const double2*)(XT + (size_t)(k0 + ch * 64) * 64);
    double2* dst = (double2*)xs;
    for (int i = tid; i < 2048; i += 256) dst[i] = src[i];
    __syncthreads();
#pragma unroll
    for (int g = 0; g < 2; ++g) {
#pragma unroll
      for (int u = 0; u < 8; ++u) {
        int ks = g * 8 + u;
        int step = ch * 16 + ks;
        float nv = 0.f;
        if (step + 8 < 64) nv = wp[0];
        wp += (size_t)4 * GC;
        double av = (double)ab[u];
        const double* bp = xs + (ks * 4 + sub) * 64 + lane16;
        double b0 = bp[0], b1 = bp[16], b2 = bp[32], b3 = bp[48];
        a0 = __builtin_amdgcn_mfma_f64_16x16x4f64(av, b0, a0, 0, 0, 0);
        a1 = __builtin_amdgcn_mfma_f64_16x16x4f64(av, b1, a1, 0, 0, 0);
        a2 = __builtin_amdgcn_mfma_f64_16x16x4f64(av, b2, a2, 0, 0, 0);
        a3 = __builtin_amdgcn_mfma_f64_16x16x4f64(av, b3, a3, 0, 0, 0);
        ab[u] = nv;
      }
    }
  }
  __syncthreads();   // protect xs before next unit reuses it
#pragma unroll
  for (int j = 0; j < 4; ++j) {
    int m = (conv == 0) ? sub * 4 + j : (conv == 2) ? sub + 4 * j : lane16;
    int n = (conv == 0) ? lane16 : (conv == 2) ? lane16 : ((conv == 1) ? sub * 4 + j : sub + 4 * j);
    size_t base = ((size_t)slot * 64 + n) * GC + colbase + wv * 16 + m;
    part[base]                   = a0[j];
    part[base + (size_t)16 * GC] = a1[j];
    part[base + (size_t)32 * GC] = a2[j];
    part[base + (size_t)48 * GC] = a3[j];
  }
}

// cell unit: b = u&63, hcol block = u>>6
__device__ __forceinline__ void cell_unit(int u, const double* part, int sBeg, int S,
                                          const float* bias, double* c, double* hT,
                                          int emit, u16* xh, int tid) {
  int b = u & 63;
  int hcol = (u >> 6) * 256 + tid;
  double gi = (double)bias[hcol];
  double gf = (double)bias[1024 + hcol];
  double gg = (double)bias[2048 + hcol];
  double go = (double)bias[3072 + hcol];
#pragma unroll 4
  for (int s = sBeg; s < sBeg + S; ++s) {
    const double* p = part + ((size_t)s * 64 + b) * GC;
    gi += p[hcol]; gf += p[1024 + hcol]; gg += p[2048 + hcol]; go += p[3072 + hcol];
  }
  size_t ci = (size_t)b * HSZ + hcol;
  double cn = dsig(gf) * c[ci] + dsig(gi) * tanh(gg);
  double hn = dsig(go) * tanh(cn);
  c[ci] = cn;
  hT[(size_t)hcol * 64 + b] = hn;
  if (emit)
    xh[(size_t)(hcol >> 7) * 8192 + (size_t)b * 128 + (hcol & 127)] = f2bf((float)hn);
}

// FC bf16 unit: vbase = u*64
__device__ __forceinline__ void fcbf_unit(int u, const u16* xhg, const u16* whT, const float* fcb,
                                          double* candV, int* candI, double* xs, int tid) {
  u16* lx = (u16*)xs;
  int l = tid & 63, wv = tid >> 6;
  int sub = l >> 4, lane16 = l & 15;
  int vbase = u * 64;
  int colA = min(vbase + wv * 16 + lane16, VSZ - 1);
  const u16* wrow = whT + (size_t)colA * 1024;
  f32x4v acc0 = {0,0,0,0}, acc1 = {0,0,0,0}, acc2 = {0,0,0,0}, acc3 = {0,0,0,0};
  for (int ch = 0; ch < 8; ++ch) {
    bf16x8 wh0 = *(const bf16x8*)(wrow + ch * 128 + 0 * 32 + sub * 8);
    bf16x8 wh1 = *(const bf16x8*)(wrow + ch * 128 + 1 * 32 + sub * 8);
    bf16x8 wh2 = *(const bf16x8*)(wrow + ch * 128 + 2 * 32 + sub * 8);
    bf16x8 wh3 = *(const bf16x8*)(wrow + ch * 128 + 3 * 32 + sub * 8);
    __syncthreads();
    {
      const uint4* sg = (const uint4*)(xhg + (size_t)ch * 8192);
      uint4* dl = (uint4*)lx;
#pragma unroll
      for (int i = 0; i < 4; ++i) {
        int uu = tid + i * 256;
        int bswz = uu >> 4, g = uu & 15;
        dl[(bswz << 4) | (g ^ (bswz & 7))] = sg[uu];
      }
    }
    __syncthreads();
#pragma unroll
    for (int kt = 0; kt < 4; ++kt) {
      bf16x8 whv = (kt == 0) ? wh0 : (kt == 1) ? wh1 : (kt == 2) ? wh2 : wh3;
#define BT_STEP(BT, ACC) {                                                              \
        int bb = BT * 16 + lane16;                                                      \
        const bf16x8* bp2 = (const bf16x8*)lx + ((bb << 4) | ((kt * 4 + sub) ^ (bb & 7))); \
        ACC = __builtin_amdgcn_mfma_f32_16x16x32_bf16(whv, *bp2, ACC, 0, 0, 0); }
      BT_STEP(0, acc0)
      BT_STEP(1, acc1)
      BT_STEP(2, acc2)
      BT_STEP(3, acc3)
#undef BT_STEP
    }
  }
  __syncthreads();
#pragma unroll
  for (int j = 0; j < 4; ++j) {
    int vl = wv * 16 + sub * 4 + j;
    int v = vbase + vl;
    bool okv = (v < VSZ);
    double bi = okv ? (double)fcb[min(v, VSZ - 1)] : 0.0;
    int b0i = lane16, b1i = 16 + lane16, b2i = 32 + lane16, b3i = 48 + lane16;
    xs[b0i * 64 + ((vl + b0i) & 63)] = okv ? ((double)acc0[j] + bi) / 0.75 : -INFINITY;
    xs[b1i * 64 + ((vl + b1i) & 63)] = okv ? ((double)acc1[j] + bi) / 0.75 : -INFINITY;
    xs[b2i * 64 + ((vl + b2i) & 63)] = okv ? ((double)acc2[j] + bi) / 0.75 : -INFINITY;
    xs[b3i * 64 + ((vl + b3i) & 63)] = okv ? ((double)acc3[j] + bi) / 0.75 : -INFINITY;
  }
  __syncthreads();
  if (tid < 64) {
    int b = tid;
    double tv[5]; int ti[5];
#pragma unroll
    for (int p = 0; p < 5; ++p) { tv[p] = -INFINITY; ti[p] = INT_MAX; }
    for (int vl2 = 0; vl2 < 64; ++vl2)
      ins5(xs[b * 64 + ((vl2 + b) & 63)], vbase + vl2, tv, ti);
#pragma unroll
    for (int r = 0; r < 5; ++r) {
      candV[(size_t)b * NCAND + u * 5 + r] = tv[r];
      candI[(size_t)b * NCAND + u * 5 + r] = ti[r];
    }
  }
  __syncthreads();
}

// FC f64-MFMA unit (fallback path)
__device__ __forceinline__ void fcf64_unit(int u, const double* h1T, const float* W, const float* fcb,
                                           double* candV, int* candI, int conv, double* xs, int tid) {
  int l = tid & 63, wv = tid >> 6;
  int sub = l >> 4, lane16 = l & 15;
  int vbase = u * 64;
  int colA = min(vbase + wv * 16 + lane16, VSZ - 1);
  f64x4 a0 = {0.,0.,0.,0.}, a1 = {0.,0.,0.,0.}, a2 = {0.,0.,0.,0.}, a3 = {0.,0.,0.,0.};
  const float* wp = W + (size_t)sub * VSZ + colA;
  float ab[8];
#pragma unroll
  for (int uu = 0; uu < 8; ++uu) { ab[uu] = wp[0]; wp += (size_t)4 * VSZ; }
  for (int ch = 0; ch < 16; ++ch) {
    __syncthreads();
    const double2* src = (const double2*)(h1T + (size_t)ch * 64 * 64);
    double2* dst = (double2*)xs;
    for (int i = tid; i < 2048; i += 256) dst[i] = src[i];
    __syncthreads();
#pragma unroll
    for (int g = 0; g < 2; ++g) {
#pragma unroll
      for (int uu = 0; uu < 8; ++uu) {
        int ks = g * 8 + uu;
        int step = ch * 16 + ks;
        float nv = 0.f;
        if (step + 8 < 256) nv = wp[0];
        wp += (size_t)4 * VSZ;
        double av = (double)ab[uu];
        const double* bp = xs + (ks * 4 + sub) * 64 + lane16;
        double b0 = bp[0], b1 = bp[16], b2 = bp[32], b3 = bp[48];
        a0 = __builtin_amdgcn_mfma_f64_16x16x4f64(av, b0, a0, 0, 0, 0);
        a1 = __builtin_amdgcn_mfma_f64_16x16x4f64(av, b1, a1, 0, 0, 0);
        a2 = __builtin_amdgcn_mfma_f64_16x16x4f64(av, b2, a2, 0, 0, 0);
        a3 = __builtin_amdgcn_mfma_f64_16x16x4f64(av, b3, a3, 0, 0, 0);
        ab[uu] = nv;
      }
    }
  }
  __syncthreads();
#pragma unroll
  for (int j = 0; j < 4; ++j) {
    int m = (conv == 0) ? sub * 4 + j : (conv == 2) ? sub + 4 * j : lane16;
    int n = (conv == 0) ? lane16 : (conv == 2) ? lane16 : ((conv == 1) ? sub * 4 + j : sub + 4 * j);
    int vl = wv * 16 + m;
    int v = vbase + vl;
    bool okv = (v < VSZ);
    double bi = okv ? (double)fcb[min(v, VSZ - 1)] : 0.0;
    int b0i = n, b1i = 16 + n, b2i = 32 + n, b3i = 48 + n;
    xs[b0i * 64 + ((vl + b0i) & 63)] = okv ? (a0[j] + bi) / 0.75 : -INFINITY;
    xs[b1i * 64 + ((vl + b1i) & 63)] = okv ? (a1[j] + bi) / 0.75 : -INFINITY;
    xs[b2i * 64 + ((vl + b2i) & 63)] = okv ? (a2[j] + bi) / 0.75 : -INFINITY;
    xs[b3i * 64 + ((vl + b3i) & 63)] = okv ? (a3[j] + bi) / 0.75 : -INFINITY;
  }
  __syncthreads();
  if (tid < 64) {
    int b = tid;
    double tv[5]; int ti[5];
#pragma unroll
    for (int p = 0; p < 5; ++p) { tv[p] = -INFINITY; ti[p] = INT_MAX; }
    for (int vl2 = 0; vl2 < 64; ++vl2)
      ins5(xs[b * 64 + ((vl2 + b) & 63)], vbase + vl2, tv, ti);
#pragma unroll
    for (int r = 0; r < 5; ++r) {
      candV[(size_t)b * NCAND + u * 5 + r] = tv[r];
      candI[(size_t)b * NCAND + u * 5 + r] = ti[r];
    }
  }
  __syncthreads();
}

// rfin unit: one batch row b; uses smem as sv/si; small shared scratch passed in
__device__ __forceinline__ void rfin_unit(int b, const double* candV, const int* candI,
                                          const float* W, const float* fcb, const double* h1T,
                                          const double* gum, int t, const float* embed,
                                          float* out, double* xt0, char* smem,
                                          double* exS, float* wvv, int* wvi, int* wvs, int tid) {
  float* sv = (float*)smem;
  int*   si = (int*)(smem + NCAND * 4);
  int l = tid & 63, wvd = tid >> 6;
  for (int e = tid; e < NCAND; e += 256) {
    sv[e] = (float)candV[(size_t)b * NCAND + e];
    si[e] = candI[(size_t)b * NCAND + e];
  }
  __syncthreads();
  int cidx[NREF];
#pragma unroll
  for (int r = 0; r < NREF; ++r) {
    float bv = -INFINITY; int bi = INT_MAX, bs = 0;
    for (int e = tid; e < NCAND; e += 256) {
      float v = sv[e]; int i2 = si[e];
      if (v > bv || (v == bv && i2 < bi)) { bv = v; bi = i2; bs = e; }
    }
#pragma unroll
    for (int off = 1; off < 64; off <<= 1) {
      float ov = __shfl_xor(bv, off, 64);
      int oi = __shfl_xor(bi, off, 64);
      int os = __shfl_xor(bs, off, 64);
      if (ov > bv || (ov == bv && oi < bi)) { bv = ov; bi = oi; bs = os; }
    }
    if (l == 0) { wvv[wvd] = bv; wvi[wvd] = bi; wvs[wvd] = bs; }
    __syncthreads();
    float fv = wvv[0]; int fi = wvi[0], fs = wvs[0];
#pragma unroll
    for (int q = 1; q < 4; ++q) {
      float ov = wvv[q]; int oi = wvi[q], os = wvs[q];
      if (ov > fv || (ov == fv && oi < fi)) { fv = ov; fi = oi; fs = os; }
    }
    cidx[r] = fi;
    __syncthreads();
    if (tid == 0) sv[fs] = -INFINITY;
    __syncthreads();
  }
#pragma unroll
  for (int rr = 0; rr < 4; ++rr) {
    int c = wvd + rr * 4;
    int vc = cidx[c];
    double p = 0.0;
#pragma unroll
    for (int i = 0; i < 16; ++i) {
      int k = i * 64 + l;
      p = fma((double)W[(size_t)k * VSZ + vc], h1T[(size_t)k * 64 + b], p);
    }
#pragma unroll
    for (int off = 1; off < 64; off <<= 1) p += __shfl_xor(p, off, 64);
    if (l == 0) exS[c] = (p + (double)fcb[vc]) / 0.75;
  }
  __syncthreads();
  double tv[5]; int ti[5];
#pragma unroll
  for (int p = 0; p < 5; ++p) { tv[p] = -INFINITY; ti[p] = INT_MAX; }
#pragma unroll
  for (int c = 0; c < NREF; ++c) ins5(exS[c], cidx[c], tv, ti);
  const double* g = gum + (size_t)t * 320 + b * 5;
  double bestv = tv[0] + g[0]; int best = 0;
#pragma unroll
  for (int k2 = 1; k2 < 5; ++k2) { double vv2 = tv[k2] + g[k2]; if (vv2 > bestv) { bestv = vv2; best = k2; } }
  int nxt = ti[best];
  if (tid == 0) {
    out[b * TSZ + t] = (float)nxt;
    double m = tv[0];
    double exx[5]; double s = 0.0;
#pragma unroll
    for (int k2 = 0; k2 < 5; ++k2) { exx[k2] = exp(tv[k2] - m); s += exx[k2]; }
    float* po = out + BSZ * TSZ + ((size_t)b * TSZ + t) * 5;
#pragma unroll
    for (int k2 = 0; k2 < 5; ++k2) po[k2] = (float)(exx[k2] / s);
  }
  xt0[(size_t)tid * 64 + b] = (double)embed[(size_t)nxt * ESZ + tid];
  __syncthreads();
}

// ================= cooperative megakernel: all 80 steps, 6 grid syncs/step =================
struct MArgs {
  double *xt0, *h0T, *h1T, *c0, *c1, *part, *gum, *candV;
  int *candI, *fbuf;
  u16 *xhg, *whT;
  const float *w_ih0, *w_hh0, *b0, *w_ih1, *w_hh1, *b1, *fc_w, *fc_b, *embed;
  float *out;
  int useBF;
};

__global__ __launch_bounds__(256, 3) void k_mega(MArgs A) {
  cg::grid_group grid = cg::this_grid();
  __shared__ alignas(16) char smem[32768];
  __shared__ double exS[NREF];
  __shared__ float wvv[4]; __shared__ int wvi[4]; __shared__ int wvs[4];
  double* xs = (double*)smem;
  int tid = threadIdx.x;
  int conv = A.fbuf[0] & 3;
  int bf = A.useBF && (A.fbuf[2] != 0);
  double* part9 = A.part + (size_t)9 * 64 * GC;
  for (int t = 0; t < TSZ; ++t) {
    // LSTM-A: 576 units (1:1 with grid). s=u>>6: 0=xt0*w_ih0, 1-4=h0*w_hh0, 5-8=h1*w_hh1
    for (int u = blockIdx.x; u < 576; u += gridDim.x) {
      int cb = u & 63, s = u >> 6;
      const double* XT; const float* W; int k0;
      if (s < 1)      { XT = A.xt0; W = A.w_ih0; k0 = 0; }
      else if (s < 5) { XT = A.h0T; W = A.w_hh0; k0 = (s - 1) * 256; }
      else            { XT = A.h1T; W = A.w_hh1; k0 = (s - 5) * 256; }
      lstm_unit(cb, s, XT, W, k0, A.part, conv, xs, tid);
    }
    grid.sync();
    // cell layer 0: slots 0..4
    for (int u = blockIdx.x; u < 256; u += gridDim.x)
      cell_unit(u, A.part, 0, 5, A.b0, A.c0, A.h0T, 0, A.xhg, tid);
    grid.sync();
    // LSTM-B: 256 units -> slots 9..12 (h0n * w_ih1)
    for (int u = blockIdx.x; u < 256; u += gridDim.x) {
      int cb = u & 63, s = u >> 6;
      lstm_unit(cb, 9 + s, A.h0T, A.w_ih1, s * 256, A.part, conv, xs, tid);
    }
    grid.sync();
    // cell layer 1: slots 5..12
    for (int u = blockIdx.x; u < 256; u += gridDim.x)
      cell_unit(u, A.part, 5, 8, A.b1, A.c1, A.h1T, 1, A.xhg, tid);
    grid.sync();
    // FC: 786 units
    if (bf) {
      for (int u = blockIdx.x; u < NFCB; u += gridDim.x)
        fcbf_unit(u, A.xhg, A.whT, A.fc_b, A.candV, A.candI, xs, tid);
    } else {
      for (int u = blockIdx.x; u < NFCB; u += gridDim.x)
        fcf64_unit(u, A.h1T, A.fc_w, A.fc_b, A.candV, A.candI, conv, xs, tid);
    }
    grid.sync();
    // refine + finalize: 64 units
    for (int u = blockIdx.x; u < 64; u += gridDim.x)
      rfin_unit(u, A.candV, A.candI, A.fc_w, A.fc_b, A.h1T, A.gum, t, A.embed,
                A.out, A.xt0, smem, exS, wvv, wvi, wvs, tid);
    grid.sync();
  }
}

// ================= fallback per-step kernels (R16-proven, used if coop launch fails) =================

__global__ __launch_bounds__(256, 4) void k_lstm_mfma(const double* __restrict__ x0, const float* __restrict__ W0,
                                                      const double* __restrict__ x1, const float* __restrict__ W1,
                                                      const double* __restrict__ x2, const float* __restrict__ W2,
                                                      int s1, int s2, double* __restrict__ part,
                                                      const int* __restrict__ fbp) {
  __shared__ double xs[64 * 64];
  int s = blockIdx.y;
  const double* XT; const float* W; int k0;
  if (s < s1)      { XT = x0; W = W0; k0 = s * 256; }
  else if (s < s2) { XT = x1; W = W1; k0 = (s - s1) * 256; }
  else             { XT = x2; W = W2; k0 = (s - s2) * 256; }
  lstm_unit(blockIdx.x, s, XT, W, k0, part, fbp[0] & 3, xs, threadIdx.x);
}

__global__ __launch_bounds__(256) void k_cell(const double* __restrict__ part, int sBeg, int S,
                                              const float* __restrict__ bias,
                                              double* __restrict__ c, double* __restrict__ hT,
                                              int emit, u16* __restrict__ xh) {
  cell_unit(blockIdx.x * 64 + blockIdx.y, part, sBeg, S, bias, c, hT, emit, xh, threadIdx.x);
}

__global__ __launch_bounds__(256, 4) void k_fcbf(const u16* __restrict__ xhg, const u16* __restrict__ whT,
                                                 const float* __restrict__ fcb,
                                                 double* __restrict__ candV, int* __restrict__ candI,
                                                 const int* __restrict__ fbp) {
  __shared__ double xs[64 * 64];
  fcbf_unit(blockIdx.x, xhg, whT, fcb, candV, candI, xs, threadIdx.x);
}

__global__ __launch_bounds__(256, 4) void k_fcf64(const double* __restrict__ h1T, const float* __restrict__ W,
                                                  const float* __restrict__ fcb,
                                                  double* __restrict__ candV, int* __restrict__ candI,
                                                  const int* __restrict__ fbp) {
  __shared__ double xs[64 * 64];
  fcf64_unit(blockIdx.x, h1T, W, fcb, candV, candI, fbp[0] & 3, xs, threadIdx.x);
}

__global__ __launch_bounds__(256) void k_rfin(const double* __restrict__ candV, const int* __restrict__ candI,
                                              const float* __restrict__ W, const float* __restrict__ fcb,
                                              const double* __restrict__ h1T,
                                              const double* __restrict__ gum, int t,
                                              const float* __restrict__ embed,
                                              float* __restrict__ out, double* __restrict__ xt0) {
  __shared__ alignas(16) char smem[32768];
  __shared__ double exS[NREF];
  __shared__ float wvv[4]; __shared__ int wvi[4]; __shared__ int wvs[4];
  rfin_unit(blockIdx.x, candV, candI, W, fcb, h1T, gum, t, embed, out, xt0,
            smem, exS, wvv, wvi, wvs, threadIdx.x);
}

// -------- initial embedding of SOS --------
__global__ __launch_bounds__(256) void k_emb0(const float* __restrict__ embed, const int* __restrict__ sos,
                                              double* __restrict__ xt0) {
  int idx = blockIdx.x * 256 + threadIdx.x;
  int b = idx & 63, k = idx >> 6;
  xt0[(size_t)k * 64 + b] = (double)embed[(size_t)sos[0] * ESZ + k];
}

extern "C" void kernel_launch(void* const* d_in, const int* in_sizes, int n_in,
                              void* d_out, int out_size, void* d_ws, size_t ws_size,
                              hipStream_t stream) {
  const float* hours = (const float*)d_in[0];
  const float* tp_w1 = (const float*)d_in[1];
  const float* tp_b1 = (const float*)d_in[2];
  const float* tp_w2 = (const float*)d_in[3];
  const float* tp_b2 = (const float*)d_in[4];
  const float* embed = (const float*)d_in[5];
  const float* w_ih0 = (const float*)d_in[6];
  const float* w_hh0 = (const float*)d_in[7];
  const float* b0    = (const float*)d_in[8];
  const float* w_ih1 = (const float*)d_in[9];
  const float* w_hh1 = (const float*)d_in[10];
  const float* b1    = (const float*)d_in[11];
  const float* fc_w  = (const float*)d_in[12];
  const float* fc_b  = (const float*)d_in[13];
  const int*   sos   = (const int*)d_in[14];
  float* out = (float*)d_out;

  char* w = (char*)d_ws;
  double* part = (double*)w;  w += (size_t)NSLOT * 64 * GC * 8;   // 27.3 MB lstm partials
  double* xt0  = (double*)w;  w += (size_t)ESZ * 64 * 8;
  double* h0T  = (double*)w;  w += (size_t)HSZ * 64 * 8;
  double* h1T  = (double*)w;  w += (size_t)HSZ * 64 * 8;
  double* c0   = (double*)w;  w += (size_t)BSZ * HSZ * 8;
  double* c1   = (double*)w;  w += (size_t)BSZ * HSZ * 8;
  double* tp1T = (double*)w;  w += (size_t)HSZ * 64 * 8;
  double* gum  = (double*)w;  w += (size_t)TSZ * 320 * 8;
  double* candV = (double*)w; w += (size_t)BSZ * NCAND * 8;       // 2.01 MB, b-major
  int*    candI = (int*)w;    w += (size_t)BSZ * NCAND * 4;       // 1.01 MB
  int*    fbuf  = (int*)w;    w += 64;                            // [0]=f64 conv, [2]=bf16 ok
  u16*    xhg   = (u16*)w;    w += (size_t)HSZ * 64 * 2;          // 128 KB bf16 h1 (chunk layout)
  u16*    whT   = (u16*)w;    w += (size_t)VSZ * 1024 * 2;        // 102.9 MB transposed bf16 fc_w
  size_t need = (size_t)(w - (char*)d_ws);
  int useBF = (ws_size >= need) ? 1 : 0;

  k_probe<<<dim3(1), dim3(64), 0, stream>>>(fbuf);
  k_rng<<<dim3(100), dim3(256), 0, stream>>>(gum);
  k_time1<<<dim3(256), dim3(256), 0, stream>>>(hours, tp_w1, tp_b1, tp1T);
  k_gemm_simple<<<dim3(16, 8), dim3(256), 0, stream>>>(tp1T, tp_w2, 1024, 8, part);
  k_t2r<<<dim3(16, 64), dim3(256), 0, stream>>>(part, tp_b2, h0T, c0, h1T, c1);
  k_emb0<<<dim3(64), dim3(256), 0, stream>>>(embed, sos, xt0);
  if (useBF)
    k_wconv<<<dim3(786, 16), dim3(256), 0, stream>>>(fc_w, whT);

  MArgs A;
  A.xt0 = xt0; A.h0T = h0T; A.h1T = h1T; A.c0 = c0; A.c1 = c1; A.part = part;
  A.gum = gum; A.candV = candV; A.candI = candI; A.fbuf = fbuf; A.xhg = xhg; A.whT = whT;
  A.w_ih0 = w_ih0; A.w_hh0 = w_hh0; A.b0 = b0; A.w_ih1 = w_ih1; A.w_hh1 = w_hh1; A.b1 = b1;
  A.fc_w = fc_w; A.fc_b = fc_b; A.embed = embed; A.out = out; A.useBF = useBF;
  void* kargs[] = { (void*)&A };
  hipError_t ce = hipLaunchCooperativeKernel((void*)k_mega, dim3(MGRID), dim3(256), kargs, 0, stream);
  if (ce != hipSuccess) {
    // fallback: classic per-step launch chain (R16-proven)
    double* part9 = part + (size_t)9 * 64 * GC;
    for (int t = 0; t < TSZ; ++t) {
      k_lstm_mfma<<<dim3(64, 9), dim3(256), 0, stream>>>(xt0, w_ih0, h0T, w_hh0, h1T, w_hh1, 1, 5, part, fbuf);
      k_cell<<<dim3(4, 64), dim3(256), 0, stream>>>(part, 0, 5, b0, c0, h0T, 0, xhg);
      k_lstm_mfma<<<dim3(64, 4), dim3(256), 0, stream>>>(h0T, w_ih1, h0T, w_ih1, h0T, w_ih1, 4, 4, part9, fbuf);
      k_cell<<<dim3(4, 64), dim3(256), 0, stream>>>(part, 5, 8, b1, c1, h1T, 1, xhg);
      if (useBF)
        k_fcbf<<<dim3(NFCB), dim3(256), 0, stream>>>(xhg, whT, fc_b, candV, candI, fbuf);
      else
        k_fcf64<<<dim3(NFCB), dim3(256), 0, stream>>>(h1T, fc_w, fc_b, candV, candI, fbuf);
      k_rfin<<<dim3(64), dim3(256), 0, stream>>>(candV, candI, fc_w, fc_b, h1T, gum, t, embed, out, xt0);
    }
  }
}

// Round 18
// 26629.166 us; speedup vs baseline: 2.3923x; 2.3923x over previous
//
#include <hip/hip_runtime.h>
#include <math.h>
#include <stdint.h>
#include <limits.h>

#define VSZ 50257
#define ESZ 256
#define HSZ 1024
#define BSZ 64
#define TSZ 80
#define GC  4096            // 4*H gate columns
#define NFCB 786            // ceil(VSZ/64) FC col-blocks
#define NCAND (NFCB*5)      // 3930 candidates per batch row
#define NSLOT 13            // lstm part slots: A 0..8 (l0: 0..4, l1-rec: 5..8), B 9..12
#define NREF 16             // exact-refined candidates per batch row

typedef unsigned int u32;
typedef unsigned short u16;
typedef double f64x4 __attribute__((ext_vector_type(4)));
typedef float f32x4v __attribute__((ext_vector_type(4)));
typedef __bf16 bf16x8 __attribute__((ext_vector_type(8)));
union BFrag { u16 u[8]; bf16x8 v; };

__device__ __forceinline__ u16 f2bf(float f) {   // f32 -> bf16 RNE
  u32 x = __float_as_uint(f);
  return (u16)((x + 0x7FFFu + ((x >> 16) & 1u)) >> 16);
}
__device__ __forceinline__ float bf2f(u16 h) { return __uint_as_float(((u32)h) << 16); }

// ---------------- Threefry-2x32 (JAX exact) ----------------
__device__ __forceinline__ void tf2x32(u32 k0, u32 k1, u32& x0, u32& x1) {
  u32 ks2 = k0 ^ k1 ^ 0x1BD11BDAu;
  x0 += k0; x1 += k1;
#define RND(r) { x0 += x1; x1 = (x1 << r) | (x1 >> (32 - r)); x1 ^= x0; }
  RND(13) RND(15) RND(26) RND(6)
  x0 += k1; x1 += ks2 + 1u;
  RND(17) RND(29) RND(16) RND(24)
  x0 += ks2; x1 += k0 + 2u;
  RND(13) RND(15) RND(26) RND(6)
  x0 += k0; x1 += k1 + 3u;
  RND(17) RND(29) RND(16) RND(24)
  x0 += k1; x1 += ks2 + 4u;
  RND(13) RND(15) RND(26) RND(6)
  x0 += ks2; x1 += k0 + 5u;
#undef RND
}

__device__ __forceinline__ double dsig(double x) { return 0.5 + 0.5 * tanh(0.5 * x); }

// sorted-desc top5 insert; ties -> lower index first (matches lax.top_k)
__device__ __forceinline__ void ins5(double v, int i, double* tv, int* ti) {
  bool beat4 = (v > tv[4]) || (v == tv[4] && i < ti[4]);
  if (!beat4) return;
  tv[4] = v; ti[4] = i;
#pragma unroll
  for (int p = 4; p > 0; --p) {
    bool sw = (tv[p] > tv[p-1]) || (tv[p] == tv[p-1] && ti[p] < ti[p-1]);
    double a0 = sw ? tv[p] : tv[p-1]; double a1 = sw ? tv[p-1] : tv[p];
    tv[p-1] = a0; tv[p] = a1;
    int b0 = sw ? ti[p] : ti[p-1]; int b1 = sw ? ti[p-1] : ti[p];
    ti[p-1] = b0; ti[p] = b1;
  }
}

// exact integer reference D[m][n] for f64 probe: sum_k (4m+k+1)*(16k+n+1)
__device__ __forceinline__ double dref(int m, int n) {
  int s = 0;
#pragma unroll
  for (int k = 0; k < 4; ++k) s += (4*m + k + 1) * (16*k + n + 1);
  return (double)s;
}

// -------- MFMA layout probes: fb[0]=f64 conv (0..3), fb[2]=bf16 maps ok --------
__global__ __launch_bounds__(64) void k_probe(int* __restrict__ fbp) {
  int l = threadIdx.x;
  int lane16 = l & 15, sub = l >> 4;
  {
    double av = (double)(4 * lane16 + sub + 1);     // A[m=lane16][k=sub]
    double bv = (double)(16 * sub + lane16 + 1);    // B[k=sub][n=lane16]
    f64x4 acc = {0., 0., 0., 0.};
    acc = __builtin_amdgcn_mfma_f64_16x16x4f64(av, bv, acc, 0, 0, 0);
    bool o0 = true, o1 = true, o2 = true, o3 = true;
#pragma unroll
    for (int j = 0; j < 4; ++j) {
      double d = acc[j];
      o0 = o0 && (d == dref(4 * sub + j, lane16));
      o1 = o1 && (d == dref(lane16, 4 * sub + j));
      o2 = o2 && (d == dref(sub + 4 * j, lane16));
      o3 = o3 && (d == dref(lane16, sub + 4 * j));
    }
    int a0 = __all(o0), a1 = __all(o1), a2 = __all(o2), a3 = __all(o3);
    if (l == 0) { fbp[0] = a0 ? 0 : a1 ? 1 : a2 ? 2 : 3; fbp[1] = 0; }
  }
  {
    BFrag fa, fbv;
#pragma unroll
    for (int i = 0; i < 8; ++i) {
      int k = sub * 8 + i;
      fa.u[i]  = f2bf((float)((lane16 * 5 + k * 3) % 63 + 1));
      fbv.u[i] = f2bf((float)((k * 7 + lane16 * 11) % 61 + 1));
    }
    f32x4v c = {0.f, 0.f, 0.f, 0.f};
    c = __builtin_amdgcn_mfma_f32_16x16x32_bf16(fa.v, fbv.v, c, 0, 0, 0);
    bool okb = true;
#pragma unroll
    for (int j = 0; j < 4; ++j) {
      int mm = sub * 4 + j, nn = lane16;
      int ref = 0;
      for (int k = 0; k < 32; ++k) ref += ((mm*5 + k*3) % 63 + 1) * ((k*7 + nn*11) % 61 + 1);
      okb = okb && (c[j] == (float)ref);
    }
    int allb = __all(okb);
    if (l == 0) fbp[2] = allb;
  }
}

// -------- one-time: fc_w [k][v] f32 -> whT [v][k] bf16 (tiled transpose) --------
__global__ __launch_bounds__(256) void k_wconv(const float* __restrict__ W, u16* __restrict__ whT) {
  __shared__ u16 tile[64][65];
  int vb = blockIdx.x * 64, kb = blockIdx.y * 64;
  int tid = threadIdx.x;
#pragma unroll
  for (int i = 0; i < 16; ++i) {
    int r = i * 4 + (tid >> 6), c = tid & 63;
    int v = vb + c;
    tile[c][r] = (v < VSZ) ? f2bf(W[(size_t)(kb + r) * VSZ + v]) : (u16)0;
  }
  __syncthreads();
#pragma unroll
  for (int i = 0; i < 16; ++i) {
    int r = i * 4 + (tid >> 6), c = tid & 63;
    int v = vb + r;
    if (v < VSZ) whT[(size_t)v * 1024 + kb + c] = tile[r][c];
  }
}

// -------- fused RNG: gumbel[t][m] for t<80, m<320 --------
__global__ __launch_bounds__(256) void k_rng(double* __restrict__ gum) {
  int idx = blockIdx.x * 256 + threadIdx.x;
  if (idx >= TSZ * 320) return;
  int t = idx / 320, m = idx % 320;
  u32 a0 = 0u, a1 = (u32)t;
  tf2x32(0u, 42u, a0, a1);
  u32 x0 = 0u, x1 = (u32)m;
  tf2x32(a0, a1, x0, x1);
  u32 bits = x0 ^ x1;
  const float TINY = 1.17549435082228750797e-38f;  // 2^-126
  float f = __uint_as_float((bits >> 9) | 0x3f800000u) - 1.0f;
  float u = f + TINY;
  u = fmaxf(TINY, u);
  gum[idx] = -log(-log((double)u));
}

// -------- time encode stage 1 --------
__global__ __launch_bounds__(256) void k_time1(const float* __restrict__ hours, const float* __restrict__ w1,
                                               const float* __restrict__ bb1, double* __restrict__ tp1T) {
  int idx = blockIdx.x * 256 + threadIdx.x;
  int b = idx & 63, hcol = idx >> 6;
  const float TPO = (float)(2.0 * 3.14159265358979323846 / 24.0);
  float af = hours[b] * TPO;
  double a = (double)af;
  double sv = sin(a), cv = cos(a);
  double vv = tanh(sv * (double)w1[hcol] + cv * (double)w1[HSZ + hcol] + (double)bb1[hcol]);
  tp1T[(size_t)hcol * 64 + b] = vv;
}

// -------- simple split-K gemm (prologue-only, runs once) --------
__global__ __launch_bounds__(256) void k_gemm_simple(const double* __restrict__ XTa, const float* __restrict__ Wa,
                                                     int Ka, int Sa, double* __restrict__ part) {
  int j = blockIdx.x * 256 + threadIdx.x;
  if (j >= GC) return;
  int s = blockIdx.y;
  int kc = Ka / Sa, k0 = s * kc;
  double acc[BSZ];
#pragma unroll
  for (int b = 0; b < BSZ; ++b) acc[b] = 0.0;
  const float* wp = Wa + (size_t)k0 * GC + j;
  const double* xp = XTa + (size_t)k0 * 64;
  for (int k = 0; k < kc; ++k) {
    double wv = (double)wp[0]; wp += GC;
#pragma unroll
    for (int b = 0; b < BSZ; ++b) acc[b] = fma(wv, xp[b], acc[b]);
    xp += 64;
  }
  double* o = part + ((size_t)s * 64) * GC + j;
#pragma unroll
  for (int b = 0; b < BSZ; ++b) o[(size_t)b * GC] = acc[b];
}

// -------- time encode stage 2 reduce --------
__global__ __launch_bounds__(256) void k_t2r(const double* __restrict__ part, const float* __restrict__ b2,
                                             double* __restrict__ h0T, double* __restrict__ c0,
                                             double* __restrict__ h1T, double* __restrict__ c1) {
  int b = blockIdx.y;
  int j = blockIdx.x * 256 + threadIdx.x;
  double acc = (double)b2[j];
  for (int s = 0; s < 8; ++s) acc += part[((size_t)s * 64 + b) * GC + j];
  int l = j >> 11, half = (j >> 10) & 1, hcol = j & 1023;
  if (half == 0) (l ? h1T : h0T)[(size_t)hcol * 64 + b] = acc;
  else           (l ? c1 : c0)[(size_t)b * HSZ + hcol] = acc;
}

// ================= phase bodies (HW-validated in R16/R17) =================

// LSTM MFMA unit: one 64-col block x one K=256 slice -> part slot
__device__ __forceinline__ void lstm_unit(int cb, int slot, const double* XT, const float* W, int k0,
                                          double* part, int conv, double* xs, int tid) {
  int l = tid & 63, wv = tid >> 6;
  int sub = l >> 4, lane16 = l & 15;
  int colbase = cb * 64;
  int colA = colbase + wv * 16 + lane16;
  f64x4 a0 = {0.,0.,0.,0.}, a1 = {0.,0.,0.,0.}, a2 = {0.,0.,0.,0.}, a3 = {0.,0.,0.,0.};
  const float* wp = W + (size_t)(k0 + sub) * GC + colA;
  float ab[8];
#pragma unroll
  for (int u = 0; u < 8; ++u) { ab[u] = wp[0]; wp += (size_t)4 * GC; }
  for (int ch = 0; ch < 4; ++ch) {
    __syncthreads();
    const double2* src = (const double2*)(XT + (size_t)(k0 + ch * 64) * 64);
    double2* dst = (double2*)xs;
    for (int i = tid; i < 2048; i += 256) dst[i] = src[i];
    __syncthreads();
#pragma unroll
    for (int g = 0; g < 2; ++g) {
#pragma unroll
      for (int u = 0; u < 8; ++u) {
        int ks = g * 8 + u;
        int step = ch * 16 + ks;
        float nv = 0.f;
        if (step + 8 < 64) nv = wp[0];
        wp += (size_t)4 * GC;
        double av = (double)ab[u];
        const double* bp = xs + (ks * 4 + sub) * 64 + lane16;
        double b0 = bp[0], b1 = bp[16], b2 = bp[32], b3 = bp[48];
        a0 = __builtin_amdgcn_mfma_f64_16x16x4f64(av, b0, a0, 0, 0, 0);
        a1 = __builtin_amdgcn_mfma_f64_16x16x4f64(av, b1, a1, 0, 0, 0);
        a2 = __builtin_amdgcn_mfma_f64_16x16x4f64(av, b2, a2, 0, 0, 0);
        a3 = __builtin_amdgcn_mfma_f64_16x16x4f64(av, b3, a3, 0, 0, 0);
        ab[u] = nv;
      }
    }
  }
  __syncthreads();
#pragma unroll
  for (int j = 0; j < 4; ++j) {
    int m = (conv == 0) ? sub * 4 + j : (conv == 2) ? sub + 4 * j : lane16;
    int n = (conv == 0) ? lane16 : (conv == 2) ? lane16 : ((conv == 1) ? sub * 4 + j : sub + 4 * j);
    size_t base = ((size_t)slot * 64 + n) * GC + colbase + wv * 16 + m;
    part[base]                   = a0[j];
    part[base + (size_t)16 * GC] = a1[j];
    part[base + (size_t)32 * GC] = a2[j];
    part[base + (size_t)48 * GC] = a3[j];
  }
}

// cell unit: b = u&63, hcol block = u>>6
__device__ __forceinline__ void cell_unit(int u, const double* part, int sBeg, int S,
                                          const float* bias, double* c, double* hT,
                                          int emit, u16* xh, int tid) {
  int b = u & 63;
  int hcol = (u >> 6) * 256 + tid;
  double gi = (double)bias[hcol];
  double gf = (double)bias[1024 + hcol];
  double gg = (double)bias[2048 + hcol];
  double go = (double)bias[3072 + hcol];
#pragma unroll 4
  for (int s = sBeg; s < sBeg + S; ++s) {
    const double* p = part + ((size_t)s * 64 + b) * GC;
    gi += p[hcol]; gf += p[1024 + hcol]; gg += p[2048 + hcol]; go += p[3072 + hcol];
  }
  size_t ci = (size_t)b * HSZ + hcol;
  double cn = dsig(gf) * c[ci] + dsig(gi) * tanh(gg);
  double hn = dsig(go) * tanh(cn);
  c[ci] = cn;
  hT[(size_t)hcol * 64 + b] = hn;
  if (emit)
    xh[(size_t)(hcol >> 7) * 8192 + (size_t)b * 128 + (hcol & 127)] = f2bf((float)hn);
}

// FC bf16 unit: vbase = u*64
__device__ __forceinline__ void fcbf_unit(int u, const u16* xhg, const u16* whT, const float* fcb,
                                          double* candV, int* candI, double* xs, int tid) {
  u16* lx = (u16*)xs;
  int l = tid & 63, wv = tid >> 6;
  int sub = l >> 4, lane16 = l & 15;
  int vbase = u * 64;
  int colA = min(vbase + wv * 16 + lane16, VSZ - 1);
  const u16* wrow = whT + (size_t)colA * 1024;
  f32x4v acc0 = {0,0,0,0}, acc1 = {0,0,0,0}, acc2 = {0,0,0,0}, acc3 = {0,0,0,0};
  for (int ch = 0; ch < 8; ++ch) {
    bf16x8 wh0 = *(const bf16x8*)(wrow + ch * 128 + 0 * 32 + sub * 8);
    bf16x8 wh1 = *(const bf16x8*)(wrow + ch * 128 + 1 * 32 + sub * 8);
    bf16x8 wh2 = *(const bf16x8*)(wrow + ch * 128 + 2 * 32 + sub * 8);
    bf16x8 wh3 = *(const bf16x8*)(wrow + ch * 128 + 3 * 32 + sub * 8);
    __syncthreads();
    {
      const uint4* sg = (const uint4*)(xhg + (size_t)ch * 8192);
      uint4* dl = (uint4*)lx;
#pragma unroll
      for (int i = 0; i < 4; ++i) {
        int uu = tid + i * 256;
        int bswz = uu >> 4, g = uu & 15;
        dl[(bswz << 4) | (g ^ (bswz & 7))] = sg[uu];
      }
    }
    __syncthreads();
#pragma unroll
    for (int kt = 0; kt < 4; ++kt) {
      bf16x8 whv = (kt == 0) ? wh0 : (kt == 1) ? wh1 : (kt == 2) ? wh2 : wh3;
#define BT_STEP(BT, ACC) {                                                              \
        int bb = BT * 16 + lane16;                                                      \
        const bf16x8* bp2 = (const bf16x8*)lx + ((bb << 4) | ((kt * 4 + sub) ^ (bb & 7))); \
        ACC = __builtin_amdgcn_mfma_f32_16x16x32_bf16(whv, *bp2, ACC, 0, 0, 0); }
      BT_STEP(0, acc0)
      BT_STEP(1, acc1)
      BT_STEP(2, acc2)
      BT_STEP(3, acc3)
#undef BT_STEP
    }
  }
  __syncthreads();
#pragma unroll
  for (int j = 0; j < 4; ++j) {
    int vl = wv * 16 + sub * 4 + j;
    int v = vbase + vl;
    bool okv = (v < VSZ);
    double bi = okv ? (double)fcb[min(v, VSZ - 1)] : 0.0;
    int b0i = lane16, b1i = 16 + lane16, b2i = 32 + lane16, b3i = 48 + lane16;
    xs[b0i * 64 + ((vl + b0i) & 63)] = okv ? ((double)acc0[j] + bi) / 0.75 : -INFINITY;
    xs[b1i * 64 + ((vl + b1i) & 63)] = okv ? ((double)acc1[j] + bi) / 0.75 : -INFINITY;
    xs[b2i * 64 + ((vl + b2i) & 63)] = okv ? ((double)acc2[j] + bi) / 0.75 : -INFINITY;
    xs[b3i * 64 + ((vl + b3i) & 63)] = okv ? ((double)acc3[j] + bi) / 0.75 : -INFINITY;
  }
  __syncthreads();
  if (tid < 64) {
    int b = tid;
    double tv[5]; int ti[5];
#pragma unroll
    for (int p = 0; p < 5; ++p) { tv[p] = -INFINITY; ti[p] = INT_MAX; }
    for (int vl2 = 0; vl2 < 64; ++vl2)
      ins5(xs[b * 64 + ((vl2 + b) & 63)], vbase + vl2, tv, ti);
#pragma unroll
    for (int r = 0; r < 5; ++r) {
      candV[(size_t)b * NCAND + u * 5 + r] = tv[r];
      candI[(size_t)b * NCAND + u * 5 + r] = ti[r];
    }
  }
}

// FC f64-MFMA unit (fallback path)
__device__ __forceinline__ void fcf64_unit(int u, const double* h1T, const float* W, const float* fcb,
                                           double* candV, int* candI, int conv, double* xs, int tid) {
  int l = tid & 63, wv = tid >> 6;
  int sub = l >> 4, lane16 = l & 15;
  int vbase = u * 64;
  int colA = min(vbase + wv * 16 + lane16, VSZ - 1);
  f64x4 a0 = {0.,0.,0.,0.}, a1 = {0.,0.,0.,0.}, a2 = {0.,0.,0.,0.}, a3 = {0.,0.,0.,0.};
  const float* wp = W + (size_t)sub * VSZ + colA;
  float ab[8];
#pragma unroll
  for (int uu = 0; uu < 8; ++uu) { ab[uu] = wp[0]; wp += (size_t)4 * VSZ; }
  for (int ch = 0; ch < 16; ++ch) {
    __syncthreads();
    const double2* src = (const double2*)(h1T + (size_t)ch * 64 * 64);
    double2* dst = (double2*)xs;
    for (int i = tid; i < 2048; i += 256) dst[i] = src[i];
    __syncthreads();
#pragma unroll
    for (int g = 0; g < 2; ++g) {
#pragma unroll
      for (int uu = 0; uu < 8; ++uu) {
        int ks = g * 8 + uu;
        int step = ch * 16 + ks;
        float nv = 0.f;
        if (step + 8 < 256) nv = wp[0];
        wp += (size_t)4 * VSZ;
        double av = (double)ab[uu];
        const double* bp = xs + (ks * 4 + sub) * 64 + lane16;
        double b0 = bp[0], b1 = bp[16], b2 = bp[32], b3 = bp[48];
        a0 = __builtin_amdgcn_mfma_f64_16x16x4f64(av, b0, a0, 0, 0, 0);
        a1 = __builtin_amdgcn_mfma_f64_16x16x4f64(av, b1, a1, 0, 0, 0);
        a2 = __builtin_amdgcn_mfma_f64_16x16x4f64(av, b2, a2, 0, 0, 0);
        a3 = __builtin_amdgcn_mfma_f64_16x16x4f64(av, b3, a3, 0, 0, 0);
        ab[uu] = nv;
      }
    }
  }
  __syncthreads();
#pragma unroll
  for (int j = 0; j < 4; ++j) {
    int m = (conv == 0) ? sub * 4 + j : (conv == 2) ? sub + 4 * j : lane16;
    int n = (conv == 0) ? lane16 : (conv == 2) ? lane16 : ((conv == 1) ? sub * 4 + j : sub + 4 * j);
    int vl = wv * 16 + m;
    int v = vbase + vl;
    bool okv = (v < VSZ);
    double bi = okv ? (double)fcb[min(v, VSZ - 1)] : 0.0;
    int b0i = n, b1i = 16 + n, b2i = 32 + n, b3i = 48 + n;
    xs[b0i * 64 + ((vl + b0i) & 63)] = okv ? (a0[j] + bi) / 0.75 : -INFINITY;
    xs[b1i * 64 + ((vl + b1i) & 63)] = okv ? (a1[j] + bi) / 0.75 : -INFINITY;
    xs[b2i * 64 + ((vl + b2i) & 63)] = okv ? (a2[j] + bi) / 0.75 : -INFINITY;
    xs[b3i * 64 + ((vl + b3i) & 63)] = okv ? (a3[j] + bi) / 0.75 : -INFINITY;
  }
  __syncthreads();
  if (tid < 64) {
    int b = tid;
    double tv[5]; int ti[5];
#pragma unroll
    for (int p = 0; p < 5; ++p) { tv[p] = -INFINITY; ti[p] = INT_MAX; }
    for (int vl2 = 0; vl2 < 64; ++vl2)
      ins5(xs[b * 64 + ((vl2 + b) & 63)], vbase + vl2, tv, ti);
#pragma unroll
    for (int r = 0; r < 5; ++r) {
      candV[(size_t)b * NCAND + u * 5 + r] = tv[r];
      candI[(size_t)b * NCAND + u * 5 + r] = ti[r];
    }
  }
}

// rfin unit: one batch row b
__device__ __forceinline__ void rfin_unit(int b, const double* candV, const int* candI,
                                          const float* W, const float* fcb, const double* h1T,
                                          const double* gum, int t, const float* embed,
                                          float* out, double* xt0, char* smem,
                                          double* exS, float* wvv, int* wvi, int* wvs, int tid) {
  float* sv = (float*)smem;
  int*   si = (int*)(smem + NCAND * 4);
  int l = tid & 63, wvd = tid >> 6;
  for (int e = tid; e < NCAND; e += 256) {
    sv[e] = (float)candV[(size_t)b * NCAND + e];
    si[e] = candI[(size_t)b * NCAND + e];
  }
  __syncthreads();
  int cidx[NREF];
#pragma unroll
  for (int r = 0; r < NREF; ++r) {
    float bv = -INFINITY; int bi = INT_MAX, bs = 0;
    for (int e = tid; e < NCAND; e += 256) {
      float v = sv[e]; int i2 = si[e];
      if (v > bv || (v == bv && i2 < bi)) { bv = v; bi = i2; bs = e; }
    }
#pragma unroll
    for (int off = 1; off < 64; off <<= 1) {
      float ov = __shfl_xor(bv, off, 64);
      int oi = __shfl_xor(bi, off, 64);
      int os = __shfl_xor(bs, off, 64);
      if (ov > bv || (ov == bv && oi < bi)) { bv = ov; bi = oi; bs = os; }
    }
    if (l == 0) { wvv[wvd] = bv; wvi[wvd] = bi; wvs[wvd] = bs; }
    __syncthreads();
    float fv = wvv[0]; int fi = wvi[0], fs = wvs[0];
#pragma unroll
    for (int q = 1; q < 4; ++q) {
      float ov = wvv[q]; int oi = wvi[q], os = wvs[q];
      if (ov > fv || (ov == fv && oi < fi)) { fv = ov; fi = oi; fs = os; }
    }
    cidx[r] = fi;
    __syncthreads();
    if (tid == 0) sv[fs] = -INFINITY;
    __syncthreads();
  }
#pragma unroll
  for (int rr = 0; rr < 4; ++rr) {
    int c = wvd + rr * 4;
    int vc = cidx[c];
    double p = 0.0;
#pragma unroll
    for (int i = 0; i < 16; ++i) {
      int k = i * 64 + l;
      p = fma((double)W[(size_t)k * VSZ + vc], h1T[(size_t)k * 64 + b], p);
    }
#pragma unroll
    for (int off = 1; off < 64; off <<= 1) p += __shfl_xor(p, off, 64);
    if (l == 0) exS[c] = (p + (double)fcb[vc]) / 0.75;
  }
  __syncthreads();
  double tv[5]; int ti[5];
#pragma unroll
  for (int p = 0; p < 5; ++p) { tv[p] = -INFINITY; ti[p] = INT_MAX; }
#pragma unroll
  for (int c = 0; c < NREF; ++c) ins5(exS[c], cidx[c], tv, ti);
  const double* g = gum + (size_t)t * 320 + b * 5;
  double bestv = tv[0] + g[0]; int best = 0;
#pragma unroll
  for (int k2 = 1; k2 < 5; ++k2) { double vv2 = tv[k2] + g[k2]; if (vv2 > bestv) { bestv = vv2; best = k2; } }
  int nxt = ti[best];
  if (tid == 0) {
    out[b * TSZ + t] = (float)nxt;
    double m = tv[0];
    double exx[5]; double s = 0.0;
#pragma unroll
    for (int k2 = 0; k2 < 5; ++k2) { exx[k2] = exp(tv[k2] - m); s += exx[k2]; }
    float* po = out + BSZ * TSZ + ((size_t)b * TSZ + t) * 5;
#pragma unroll
    for (int k2 = 0; k2 < 5; ++k2) po[k2] = (float)(exx[k2] / s);
  }
  xt0[(size_t)tid * 64 + b] = (double)embed[(size_t)nxt * ESZ + tid];
}

// ================= per-step kernels =================

__global__ __launch_bounds__(256, 4) void k_lstm_mfma(const double* __restrict__ x0, const float* __restrict__ W0,
                                                      const double* __restrict__ x1, const float* __restrict__ W1,
                                                      const double* __restrict__ x2, const float* __restrict__ W2,
                                                      int s1, int s2, double* __restrict__ part,
                                                      const int* __restrict__ fbp) {
  __shared__ double xs[64 * 64];
  int s = blockIdx.y;
  const double* XT; const float* W; int k0;
  if (s < s1)      { XT = x0; W = W0; k0 = s * 256; }
  else if (s < s2) { XT = x1; W = W1; k0 = (s - s1) * 256; }
  else             { XT = x2; W = W2; k0 = (s - s2) * 256; }
  lstm_unit(blockIdx.x, s, XT, W, k0, part, fbp[0] & 3, xs, threadIdx.x);
}

__global__ __launch_bounds__(256) void k_cell(const double* __restrict__ part, int sBeg, int S,
                                              const float* __restrict__ bias,
                                              double* __restrict__ c, double* __restrict__ hT,
                                              int emit, u16* __restrict__ xh) {
  cell_unit(blockIdx.x * 64 + blockIdx.y, part, sBeg, S, bias, c, hT, emit, xh, threadIdx.x);
}

// merged: units 0..785 = FC (bf16 or f64); units 786..1297 = next-step LSTM-A recurrent slots 1..8
__global__ __launch_bounds__(256, 4) void k_fcmix(const u16* __restrict__ xhg, const u16* __restrict__ whT,
                                                  const double* __restrict__ h1T, const float* __restrict__ fc_w,
                                                  const float* __restrict__ fcb,
                                                  double* __restrict__ candV, int* __restrict__ candI,
                                                  const double* __restrict__ h0T,
                                                  const float* __restrict__ w_hh0, const float* __restrict__ w_hh1,
                                                  double* __restrict__ part,
                                                  const int* __restrict__ fbp, int useBF) {
  __shared__ double xs[64 * 64];
  int u = blockIdx.x;
  int conv = fbp[0] & 3;
  if (u < NFCB) {
    if (useBF && fbp[2] != 0)
      fcbf_unit(u, xhg, whT, fcb, candV, candI, xs, threadIdx.x);
    else
      fcf64_unit(u, h1T, fc_w, fcb, candV, candI, conv, xs, threadIdx.x);
  } else {
    int v = u - NFCB;                 // 0..511
    int cb = v & 63, s = v >> 6;      // s: 0..7
    const double* XT = (s < 4) ? h0T : h1T;
    const float*  W  = (s < 4) ? w_hh0 : w_hh1;
    int k0 = ((s < 4) ? s : s - 4) * 256;
    lstm_unit(cb, 1 + s, XT, W, k0, part, conv, xs, threadIdx.x);
  }
}

__global__ __launch_bounds__(256) void k_rfin(const double* __restrict__ candV, const int* __restrict__ candI,
                                              const float* __restrict__ W, const float* __restrict__ fcb,
                                              const double* __restrict__ h1T,
                                              const double* __restrict__ gum, int t,
                                              const float* __restrict__ embed,
                                              float* __restrict__ out, double* __restrict__ xt0) {
  __shared__ alignas(16) char smem[32768];
  __shared__ double exS[NREF];
  __shared__ float wvv[4]; __shared__ int wvi[4]; __shared__ int wvs[4];
  rfin_unit(blockIdx.x, candV, candI, W, fcb, h1T, gum, t, embed, out, xt0,
            smem, exS, wvv, wvi, wvs, threadIdx.x);
}

// -------- initial embedding of SOS --------
__global__ __launch_bounds__(256) void k_emb0(const float* __restrict__ embed, const int* __restrict__ sos,
                                              double* __restrict__ xt0) {
  int idx = blockIdx.x * 256 + threadIdx.x;
  int b = idx & 63, k = idx >> 6;
  xt0[(size_t)k * 64 + b] = (double)embed[(size_t)sos[0] * ESZ + k];
}

extern "C" void kernel_launch(void* const* d_in, const int* in_sizes, int n_in,
                              void* d_out, int out_size, void* d_ws, size_t ws_size,
                              hipStream_t stream) {
  const float* hours = (const float*)d_in[0];
  const float* tp_w1 = (const float*)d_in[1];
  const float* tp_b1 = (const float*)d_in[2];
  const float* tp_w2 = (const float*)d_in[3];
  const float* tp_b2 = (const float*)d_in[4];
  const float* embed = (const float*)d_in[5];
  const float* w_ih0 = (const float*)d_in[6];
  const float* w_hh0 = (const float*)d_in[7];
  const float* b0    = (const float*)d_in[8];
  const float* w_ih1 = (const float*)d_in[9];
  const float* w_hh1 = (const float*)d_in[10];
  const float* b1    = (const float*)d_in[11];
  const float* fc_w  = (const float*)d_in[12];
  const float* fc_b  = (const float*)d_in[13];
  const int*   sos   = (const int*)d_in[14];
  float* out = (float*)d_out;

  char* w = (char*)d_ws;
  double* part = (double*)w;  w += (size_t)NSLOT * 64 * GC * 8;   // 27.3 MB lstm partials
  double* xt0  = (double*)w;  w += (size_t)ESZ * 64 * 8;
  double* h0T  = (double*)w;  w += (size_t)HSZ * 64 * 8;
  double* h1T  = (double*)w;  w += (size_t)HSZ * 64 * 8;
  double* c0   = (double*)w;  w += (size_t)BSZ * HSZ * 8;
  double* c1   = (double*)w;  w += (size_t)BSZ * HSZ * 8;
  double* tp1T = (double*)w;  w += (size_t)HSZ * 64 * 8;
  double* gum  = (double*)w;  w += (size_t)TSZ * 320 * 8;
  double* candV = (double*)w; w += (size_t)BSZ * NCAND * 8;       // 2.01 MB, b-major
  int*    candI = (int*)w;    w += (size_t)BSZ * NCAND * 4;       // 1.01 MB
  int*    fbuf  = (int*)w;    w += 64;                            // [0]=f64 conv, [2]=bf16 ok
  u16*    xhg   = (u16*)w;    w += (size_t)HSZ * 64 * 2;          // 128 KB bf16 h1 (chunk layout)
  u16*    whT   = (u16*)w;    w += (size_t)VSZ * 1024 * 2;        // 102.9 MB transposed bf16 fc_w
  size_t need = (size_t)(w - (char*)d_ws);
  int useBF = (ws_size >= need) ? 1 : 0;

  k_probe<<<dim3(1), dim3(64), 0, stream>>>(fbuf);
  k_rng<<<dim3(100), dim3(256), 0, stream>>>(gum);
  k_time1<<<dim3(256), dim3(256), 0, stream>>>(hours, tp_w1, tp_b1, tp1T);
  k_gemm_simple<<<dim3(16, 8), dim3(256), 0, stream>>>(tp1T, tp_w2, 1024, 8, part);
  k_t2r<<<dim3(16, 64), dim3(256), 0, stream>>>(part, tp_b2, h0T, c0, h1T, c1);
  k_emb0<<<dim3(64), dim3(256), 0, stream>>>(embed, sos, xt0);
  if (useBF)
    k_wconv<<<dim3(786, 16), dim3(256), 0, stream>>>(fc_w, whT);
  // prologue: seed slots 1..8 for t=0 from h0(init), h1(init)
  // s=0..3 -> h0*w_hh0 (slots 1-4), s=4..7 -> h1*w_hh1 (slots 5-8) via part offset of 1 slot
  k_lstm_mfma<<<dim3(64, 8), dim3(256), 0, stream>>>(h0T, w_hh0, h1T, w_hh1, h1T, w_hh1, 4, 8,
                                                     part + (size_t)64 * GC, fbuf);

  double* part9 = part + (size_t)9 * 64 * GC;
  for (int t = 0; t < TSZ; ++t) {
    // phase 1: slot 0 = xt0 * w_ih0 (K=256) only
    k_lstm_mfma<<<dim3(64, 1), dim3(256), 0, stream>>>(xt0, w_ih0, xt0, w_ih0, xt0, w_ih0, 1, 1, part, fbuf);
    // layer-0 cell: slots 0..4
    k_cell<<<dim3(4, 64), dim3(256), 0, stream>>>(part, 0, 5, b0, c0, h0T, 0, xhg);
    // LSTM-B: slots 9..12 = h0n * w_ih1
    k_lstm_mfma<<<dim3(64, 4), dim3(256), 0, stream>>>(h0T, w_ih1, h0T, w_ih1, h0T, w_ih1, 4, 4, part9, fbuf);
    // layer-1 cell: slots 5..12 = h1*w_hh1 (5-8) + h0n*w_ih1 (9-12)
    k_cell<<<dim3(4, 64), dim3(256), 0, stream>>>(part, 5, 8, b1, c1, h1T, 1, xhg);
    // merged: FC (786 units) + next step's recurrent LSTM-A slots 1..8 (512 units)
    k_fcmix<<<dim3(NFCB + 512), dim3(256), 0, stream>>>(xhg, whT, h1T, fc_w, fc_b, candV, candI,
                                                        h0T, w_hh0, w_hh1, part, fbuf, useBF);
    // refine + finalize
    k_rfin<<<dim3(64), dim3(256), 0, stream>>>(candV, candI, fc_w, fc_b, h1T, gum, t, embed, out, xt0);
  }
}

// Round 19
// 18988.503 us; speedup vs baseline: 3.3549x; 1.4024x over previous
//
#include <hip/hip_runtime.h>
#include <math.h>
#include <stdint.h>
#include <limits.h>

#define VSZ 50257
#define ESZ 256
#define HSZ 1024
#define BSZ 64
#define TSZ 80
#define GC  4096            // 4*H gate columns
#define NFCB 786            // ceil(VSZ/64) FC col-blocks
#define NCAND (NFCB*5)      // 3930 candidates per batch row
#define NSLOT 13            // lstm part slots: A 0..8 (l0: 0..4, l1-rec: 5..8), B 9..12
#define NREF 16             // exact-refined candidates per batch row

typedef unsigned int u32;
typedef unsigned short u16;
typedef double f64x4 __attribute__((ext_vector_type(4)));
typedef float f32x4v __attribute__((ext_vector_type(4)));
typedef __bf16 bf16x8 __attribute__((ext_vector_type(8)));
union BFrag { u16 u[8]; bf16x8 v; };

__device__ __forceinline__ u16 f2bf(float f) {   // f32 -> bf16 RNE
  u32 x = __float_as_uint(f);
  return (u16)((x + 0x7FFFu + ((x >> 16) & 1u)) >> 16);
}
__device__ __forceinline__ float bf2f(u16 h) { return __uint_as_float(((u32)h) << 16); }

// ---------------- Threefry-2x32 (JAX exact) ----------------
__device__ __forceinline__ void tf2x32(u32 k0, u32 k1, u32& x0, u32& x1) {
  u32 ks2 = k0 ^ k1 ^ 0x1BD11BDAu;
  x0 += k0; x1 += k1;
#define RND(r) { x0 += x1; x1 = (x1 << r) | (x1 >> (32 - r)); x1 ^= x0; }
  RND(13) RND(15) RND(26) RND(6)
  x0 += k1; x1 += ks2 + 1u;
  RND(17) RND(29) RND(16) RND(24)
  x0 += ks2; x1 += k0 + 2u;
  RND(13) RND(15) RND(26) RND(6)
  x0 += k0; x1 += k1 + 3u;
  RND(17) RND(29) RND(16) RND(24)
  x0 += k1; x1 += ks2 + 4u;
  RND(13) RND(15) RND(26) RND(6)
  x0 += ks2; x1 += k0 + 5u;
#undef RND
}

__device__ __forceinline__ double dsig(double x) { return 0.5 + 0.5 * tanh(0.5 * x); }

// sorted-desc top5 insert; ties -> lower index first (matches lax.top_k)
__device__ __forceinline__ void ins5(double v, int i, double* tv, int* ti) {
  bool beat4 = (v > tv[4]) || (v == tv[4] && i < ti[4]);
  if (!beat4) return;
  tv[4] = v; ti[4] = i;
#pragma unroll
  for (int p = 4; p > 0; --p) {
    bool sw = (tv[p] > tv[p-1]) || (tv[p] == tv[p-1] && ti[p] < ti[p-1]);
    double a0 = sw ? tv[p] : tv[p-1]; double a1 = sw ? tv[p-1] : tv[p];
    tv[p-1] = a0; tv[p] = a1;
    int b0 = sw ? ti[p] : ti[p-1]; int b1 = sw ? ti[p-1] : ti[p];
    ti[p-1] = b0; ti[p] = b1;
  }
}

// exact integer reference D[m][n] for f64 probe: sum_k (4m+k+1)*(16k+n+1)
__device__ __forceinline__ double dref(int m, int n) {
  int s = 0;
#pragma unroll
  for (int k = 0; k < 4; ++k) s += (4*m + k + 1) * (16*k + n + 1);
  return (double)s;
}

// -------- MFMA layout probes: fb[0]=f64 conv (0..3), fb[2]=bf16 maps ok --------
__global__ __launch_bounds__(64) void k_probe(int* __restrict__ fbp) {
  int l = threadIdx.x;
  int lane16 = l & 15, sub = l >> 4;
  {
    double av = (double)(4 * lane16 + sub + 1);     // A[m=lane16][k=sub]
    double bv = (double)(16 * sub + lane16 + 1);    // B[k=sub][n=lane16]
    f64x4 acc = {0., 0., 0., 0.};
    acc = __builtin_amdgcn_mfma_f64_16x16x4f64(av, bv, acc, 0, 0, 0);
    bool o0 = true, o1 = true, o2 = true, o3 = true;
#pragma unroll
    for (int j = 0; j < 4; ++j) {
      double d = acc[j];
      o0 = o0 && (d == dref(4 * sub + j, lane16));
      o1 = o1 && (d == dref(lane16, 4 * sub + j));
      o2 = o2 && (d == dref(sub + 4 * j, lane16));
      o3 = o3 && (d == dref(lane16, sub + 4 * j));
    }
    int a0 = __all(o0), a1 = __all(o1), a2 = __all(o2), a3 = __all(o3);
    if (l == 0) { fbp[0] = a0 ? 0 : a1 ? 1 : a2 ? 2 : 3; fbp[1] = 0; }
  }
  {
    BFrag fa, fbv;
#pragma unroll
    for (int i = 0; i < 8; ++i) {
      int k = sub * 8 + i;
      fa.u[i]  = f2bf((float)((lane16 * 5 + k * 3) % 63 + 1));
      fbv.u[i] = f2bf((float)((k * 7 + lane16 * 11) % 61 + 1));
    }
    f32x4v c = {0.f, 0.f, 0.f, 0.f};
    c = __builtin_amdgcn_mfma_f32_16x16x32_bf16(fa.v, fbv.v, c, 0, 0, 0);
    bool okb = true;
#pragma unroll
    for (int j = 0; j < 4; ++j) {
      int mm = sub * 4 + j, nn = lane16;
      int ref = 0;
      for (int k = 0; k < 32; ++k) ref += ((mm*5 + k*3) % 63 + 1) * ((k*7 + nn*11) % 61 + 1);
      okb = okb && (c[j] == (float)ref);
    }
    int allb = __all(okb);
    if (l == 0) fbp[2] = allb;
  }
}

// -------- one-time: fc_w [k][v] f32 -> whT [v][k] bf16 (tiled transpose) --------
__global__ __launch_bounds__(256) void k_wconv(const float* __restrict__ W, u16* __restrict__ whT) {
  __shared__ u16 tile[64][65];
  int vb = blockIdx.x * 64, kb = blockIdx.y * 64;
  int tid = threadIdx.x;
#pragma unroll
  for (int i = 0; i < 16; ++i) {
    int r = i * 4 + (tid >> 6), c = tid & 63;       // r = k-offset, c = v-offset
    int v = vb + c;
    tile[c][r] = (v < VSZ) ? f2bf(W[(size_t)(kb + r) * VSZ + v]) : (u16)0;
  }
  __syncthreads();
#pragma unroll
  for (int i = 0; i < 16; ++i) {
    int r = i * 4 + (tid >> 6), c = tid & 63;       // r = v-offset, c = k-offset
    int v = vb + r;
    if (v < VSZ) whT[(size_t)v * 1024 + kb + c] = tile[r][c];
  }
}

// -------- fused RNG: gumbel[t][m] for t<80, m<320 --------
__global__ __launch_bounds__(256) void k_rng(double* __restrict__ gum) {
  int idx = blockIdx.x * 256 + threadIdx.x;
  if (idx >= TSZ * 320) return;
  int t = idx / 320, m = idx % 320;
  u32 a0 = 0u, a1 = (u32)t;
  tf2x32(0u, 42u, a0, a1);
  u32 x0 = 0u, x1 = (u32)m;
  tf2x32(a0, a1, x0, x1);
  u32 bits = x0 ^ x1;
  const float TINY = 1.17549435082228750797e-38f;  // 2^-126
  float f = __uint_as_float((bits >> 9) | 0x3f800000u) - 1.0f;
  float u = f + TINY;
  u = fmaxf(TINY, u);
  gum[idx] = -log(-log((double)u));
}

// -------- time encode stage 1 --------
__global__ __launch_bounds__(256) void k_time1(const float* __restrict__ hours, const float* __restrict__ w1,
                                               const float* __restrict__ bb1, double* __restrict__ tp1T) {
  int idx = blockIdx.x * 256 + threadIdx.x;  // 64*1024
  int b = idx & 63, hcol = idx >> 6;
  const float TPO = (float)(2.0 * 3.14159265358979323846 / 24.0);
  float af = hours[b] * TPO;
  double a = (double)af;
  double sv = sin(a), cv = cos(a);
  double vv = tanh(sv * (double)w1[hcol] + cv * (double)w1[HSZ + hcol] + (double)bb1[hcol]);
  tp1T[(size_t)hcol * 64 + b] = vv;
}

// -------- simple split-K gemm (prologue-only, runs once) --------
__global__ __launch_bounds__(256) void k_gemm_simple(const double* __restrict__ XTa, const float* __restrict__ Wa,
                                                     int Ka, int Sa, double* __restrict__ part) {
  int j = blockIdx.x * 256 + threadIdx.x;
  if (j >= GC) return;
  int s = blockIdx.y;
  int kc = Ka / Sa, k0 = s * kc;
  double acc[BSZ];
#pragma unroll
  for (int b = 0; b < BSZ; ++b) acc[b] = 0.0;
  const float* wp = Wa + (size_t)k0 * GC + j;
  const double* xp = XTa + (size_t)k0 * 64;
  for (int k = 0; k < kc; ++k) {
    double wv = (double)wp[0]; wp += GC;
#pragma unroll
    for (int b = 0; b < BSZ; ++b) acc[b] = fma(wv, xp[b], acc[b]);
    xp += 64;
  }
  double* o = part + ((size_t)s * 64) * GC + j;
#pragma unroll
  for (int b = 0; b < BSZ; ++b) o[(size_t)b * GC] = acc[b];
}

// -------- time encode stage 2 reduce --------
__global__ __launch_bounds__(256) void k_t2r(const double* __restrict__ part, const float* __restrict__ b2,
                                             double* __restrict__ h0T, double* __restrict__ c0,
                                             double* __restrict__ h1T, double* __restrict__ c1) {
  int b = blockIdx.y;
  int j = blockIdx.x * 256 + threadIdx.x;
  double acc = (double)b2[j];
  for (int s = 0; s < 8; ++s) acc += part[((size_t)s * 64 + b) * GC + j];
  int l = j >> 11, half = (j >> 10) & 1, hcol = j & 1023;
  if (half == 0) (l ? h1T : h0T)[(size_t)hcol * 64 + b] = acc;
  else           (l ? c1 : c0)[(size_t)b * HSZ + hcol] = acc;
}

// -------- LSTM gemm via f64 MFMA (R8/R13/R16 HW-validated); K=256/slice; part[s][b][col] --------
__global__ __launch_bounds__(256, 4) void k_lstm_mfma(const double* __restrict__ x0, const float* __restrict__ W0,
                                                      const double* __restrict__ x1, const float* __restrict__ W1,
                                                      const double* __restrict__ x2, const float* __restrict__ W2,
                                                      int s1, int s2, double* __restrict__ part,
                                                      const int* __restrict__ fbp) {
  int conv = fbp[0] & 3;
  __shared__ double xs[64 * 64];   // 32KB x-chunk [k][b]
  int tid = threadIdx.x;
  int l = tid & 63, wv = tid >> 6;
  int sub = l >> 4, lane16 = l & 15;
  int colbase = blockIdx.x * 64;
  int s = blockIdx.y;
  const double* XT; const float* W; int k0;
  if (s < s1)      { XT = x0; W = W0; k0 = s * 256; }
  else if (s < s2) { XT = x1; W = W1; k0 = (s - s1) * 256; }
  else             { XT = x2; W = W2; k0 = (s - s2) * 256; }
  int colA = colbase + wv * 16 + lane16;
  f64x4 a0 = {0.,0.,0.,0.}, a1 = {0.,0.,0.,0.}, a2 = {0.,0.,0.,0.}, a3 = {0.,0.,0.,0.};
  const float* wp = W + (size_t)(k0 + sub) * GC + colA;
  float ab[8];
#pragma unroll
  for (int u = 0; u < 8; ++u) { ab[u] = wp[0]; wp += (size_t)4 * GC; }
  for (int ch = 0; ch < 4; ++ch) {
    __syncthreads();
    const double2* src = (const double2*)(XT + (size_t)(k0 + ch * 64) * 64);
    double2* dst = (double2*)xs;
    for (int i = tid; i < 2048; i += 256) dst[i] = src[i];
    __syncthreads();
#pragma unroll
    for (int g = 0; g < 2; ++g) {
#pragma unroll
      for (int u = 0; u < 8; ++u) {
        int ks = g * 8 + u;
        int step = ch * 16 + ks;
        float nv = 0.f;
        if (step + 8 < 64) nv = wp[0];
        wp += (size_t)4 * GC;
        double av = (double)ab[u];
        const double* bp = xs + (ks * 4 + sub) * 64 + lane16;
        double b0 = bp[0], b1 = bp[16], b2 = bp[32], b3 = bp[48];
        a0 = __builtin_amdgcn_mfma_f64_16x16x4f64(av, b0, a0, 0, 0, 0);
        a1 = __builtin_amdgcn_mfma_f64_16x16x4f64(av, b1, a1, 0, 0, 0);
        a2 = __builtin_amdgcn_mfma_f64_16x16x4f64(av, b2, a2, 0, 0, 0);
        a3 = __builtin_amdgcn_mfma_f64_16x16x4f64(av, b3, a3, 0, 0, 0);
        ab[u] = nv;
      }
    }
  }
#pragma unroll
  for (int j = 0; j < 4; ++j) {
    int m = (conv == 0) ? sub * 4 + j : (conv == 2) ? sub + 4 * j : lane16;
    int n = (conv == 0) ? lane16 : (conv == 2) ? lane16 : ((conv == 1) ? sub * 4 + j : sub + 4 * j);
    size_t base = ((size_t)s * 64 + n) * GC + colbase + wv * 16 + m;
    part[base]                   = a0[j];
    part[base + (size_t)16 * GC] = a1[j];
    part[base + (size_t)32 * GC] = a2[j];
    part[base + (size_t)48 * GC] = a3[j];
  }
}

// -------- LSTM cell; optional bf16 emission of h in FC chunk layout [ch][b][k&127] --------
__global__ __launch_bounds__(256) void k_cell(const double* __restrict__ part, int sBeg, int S,
                                              const float* __restrict__ bias,
                                              double* __restrict__ c, double* __restrict__ hT,
                                              int emit, u16* __restrict__ xh) {
  int b = blockIdx.y;
  int hcol = blockIdx.x * 256 + threadIdx.x;
  double gi = (double)bias[hcol];
  double gf = (double)bias[1024 + hcol];
  double gg = (double)bias[2048 + hcol];
  double go = (double)bias[3072 + hcol];
#pragma unroll 4
  for (int s = sBeg; s < sBeg + S; ++s) {
    const double* p = part + ((size_t)s * 64 + b) * GC;
    gi += p[hcol]; gf += p[1024 + hcol]; gg += p[2048 + hcol]; go += p[3072 + hcol];
  }
  size_t ci = (size_t)b * HSZ + hcol;
  double cn = dsig(gf) * c[ci] + dsig(gi) * tanh(gg);
  double hn = dsig(go) * tanh(cn);
  c[ci] = cn;
  hT[(size_t)hcol * 64 + b] = hn;
  if (emit)
    xh[(size_t)(hcol >> 7) * 8192 + (size_t)b * 128 + (hcol & 127)] = f2bf((float)hn);
}

// -------- FC approx via bf16 MFMA (preconverted whT) + per-block top5 --------
__global__ __launch_bounds__(256, 4) void k_fcbf(const u16* __restrict__ xhg, const u16* __restrict__ whT,
                                                 const float* __restrict__ fcb,
                                                 double* __restrict__ candV, int* __restrict__ candI,
                                                 const int* __restrict__ fbp) {
  if (fbp[2] == 0) return;
  __shared__ double xs[64 * 64];     // phase 1: 16KB swizzled xh tile; phase 2: transpose buffer
  u16* lx = (u16*)xs;
  int tid = threadIdx.x;
  int l = tid & 63, wv = tid >> 6;
  int sub = l >> 4, lane16 = l & 15;
  int vbase = blockIdx.x * 64;
  int colA = min(vbase + wv * 16 + lane16, VSZ - 1);
  const u16* wrow = whT + (size_t)colA * 1024;
  f32x4v acc0 = {0,0,0,0}, acc1 = {0,0,0,0}, acc2 = {0,0,0,0}, acc3 = {0,0,0,0};
  for (int ch = 0; ch < 8; ++ch) {
    bf16x8 wh0 = *(const bf16x8*)(wrow + ch * 128 + 0 * 32 + sub * 8);
    bf16x8 wh1 = *(const bf16x8*)(wrow + ch * 128 + 1 * 32 + sub * 8);
    bf16x8 wh2 = *(const bf16x8*)(wrow + ch * 128 + 2 * 32 + sub * 8);
    bf16x8 wh3 = *(const bf16x8*)(wrow + ch * 128 + 3 * 32 + sub * 8);
    __syncthreads();
    {
      const uint4* sg = (const uint4*)(xhg + (size_t)ch * 8192);
      uint4* dl = (uint4*)lx;
#pragma unroll
      for (int i = 0; i < 4; ++i) {
        int u = tid + i * 256;               // unit = b*16 + g (g = k'/8)
        int bswz = u >> 4, g = u & 15;
        dl[(bswz << 4) | (g ^ (bswz & 7))] = sg[u];  // XOR-swizzle kills bank conflicts
      }
    }
    __syncthreads();
#pragma unroll
    for (int kt = 0; kt < 4; ++kt) {
      bf16x8 whv = (kt == 0) ? wh0 : (kt == 1) ? wh1 : (kt == 2) ? wh2 : wh3;
#define BT_STEP(BT, ACC) {                                                              \
        int bb = BT * 16 + lane16;                                                      \
        const bf16x8* bp2 = (const bf16x8*)lx + ((bb << 4) | ((kt * 4 + sub) ^ (bb & 7))); \
        ACC = __builtin_amdgcn_mfma_f32_16x16x32_bf16(whv, *bp2, ACC, 0, 0, 0); }
      BT_STEP(0, acc0)
      BT_STEP(1, acc1)
      BT_STEP(2, acc2)
      BT_STEP(3, acc3)
#undef BT_STEP
    }
  }
  __syncthreads();   // staging reads done; reuse xs as transpose buffer
  // D: m=(l>>4)*4+j (vocab), n=lane16 (+bt*16) (batch)  [probe-verified, R11/R13/R16-validated]
#pragma unroll
  for (int j = 0; j < 4; ++j) {
    int vl = wv * 16 + sub * 4 + j;
    int v = vbase + vl;
    bool okv = (v < VSZ);
    double bi = okv ? (double)fcb[min(v, VSZ - 1)] : 0.0;
    int b0i = lane16, b1i = 16 + lane16, b2i = 32 + lane16, b3i = 48 + lane16;
    xs[b0i * 64 + ((vl + b0i) & 63)] = okv ? ((double)acc0[j] + bi) / 0.75 : -INFINITY;
    xs[b1i * 64 + ((vl + b1i) & 63)] = okv ? ((double)acc1[j] + bi) / 0.75 : -INFINITY;
    xs[b2i * 64 + ((vl + b2i) & 63)] = okv ? ((double)acc2[j] + bi) / 0.75 : -INFINITY;
    xs[b3i * 64 + ((vl + b3i) & 63)] = okv ? ((double)acc3[j] + bi) / 0.75 : -INFINITY;
  }
  __syncthreads();
  if (tid < 64) {
    int b = tid;
    double tv[5]; int ti[5];
#pragma unroll
    for (int p = 0; p < 5; ++p) { tv[p] = -INFINITY; ti[p] = INT_MAX; }
    for (int vl2 = 0; vl2 < 64; ++vl2)
      ins5(xs[b * 64 + ((vl2 + b) & 63)], vbase + vl2, tv, ti);
#pragma unroll
    for (int r = 0; r < 5; ++r) {
      candV[(size_t)b * NCAND + blockIdx.x * 5 + r] = tv[r];
      candI[(size_t)b * NCAND + blockIdx.x * 5 + r] = ti[r];
    }
  }
}

// -------- FC via f64 MFMA (launched only when ws too small for whT) --------
__global__ __launch_bounds__(256, 4) void k_fcf64(const double* __restrict__ h1T, const float* __restrict__ W,
                                                  const float* __restrict__ fcb,
                                                  double* __restrict__ candV, int* __restrict__ candI,
                                                  const int* __restrict__ fbp) {
  int conv = fbp[0] & 3;
  __shared__ double xs[64 * 64];
  int tid = threadIdx.x;
  int l = tid & 63, wv = tid >> 6;
  int sub = l >> 4, lane16 = l & 15;
  int vbase = blockIdx.x * 64;
  int colA = min(vbase + wv * 16 + lane16, VSZ - 1);
  f64x4 a0 = {0.,0.,0.,0.}, a1 = {0.,0.,0.,0.}, a2 = {0.,0.,0.,0.}, a3 = {0.,0.,0.,0.};
  const float* wp = W + (size_t)sub * VSZ + colA;
  float ab[8];
#pragma unroll
  for (int u = 0; u < 8; ++u) { ab[u] = wp[0]; wp += (size_t)4 * VSZ; }
  for (int ch = 0; ch < 16; ++ch) {
    __syncthreads();
    const double2* src = (const double2*)(h1T + (size_t)ch * 64 * 64);
    double2* dst = (double2*)xs;
    for (int i = tid; i < 2048; i += 256) dst[i] = src[i];
    __syncthreads();
#pragma unroll
    for (int g = 0; g < 2; ++g) {
#pragma unroll
      for (int u = 0; u < 8; ++u) {
        int ks = g * 8 + u;
        int step = ch * 16 + ks;
        float nv = 0.f;
        if (step + 8 < 256) nv = wp[0];
        wp += (size_t)4 * VSZ;
        double av = (double)ab[u];
        const double* bp = xs + (ks * 4 + sub) * 64 + lane16;
        double b0 = bp[0], b1 = bp[16], b2 = bp[32], b3 = bp[48];
        a0 = __builtin_amdgcn_mfma_f64_16x16x4f64(av, b0, a0, 0, 0, 0);
        a1 = __builtin_amdgcn_mfma_f64_16x16x4f64(av, b1, a1, 0, 0, 0);
        a2 = __builtin_amdgcn_mfma_f64_16x16x4f64(av, b2, a2, 0, 0, 0);
        a3 = __builtin_amdgcn_mfma_f64_16x16x4f64(av, b3, a3, 0, 0, 0);
        ab[u] = nv;
      }
    }
  }
  __syncthreads();
#pragma unroll
  for (int j = 0; j < 4; ++j) {
    int m = (conv == 0) ? sub * 4 + j : (conv == 2) ? sub + 4 * j : lane16;
    int n = (conv == 0) ? lane16 : (conv == 2) ? lane16 : ((conv == 1) ? sub * 4 + j : sub + 4 * j);
    int vl = wv * 16 + m;
    int v = vbase + vl;
    bool okv = (v < VSZ);
    double bi = okv ? (double)fcb[min(v, VSZ - 1)] : 0.0;
    int b0i = n, b1i = 16 + n, b2i = 32 + n, b3i = 48 + n;
    xs[b0i * 64 + ((vl + b0i) & 63)] = okv ? (a0[j] + bi) / 0.75 : -INFINITY;
    xs[b1i * 64 + ((vl + b1i) & 63)] = okv ? (a1[j] + bi) / 0.75 : -INFINITY;
    xs[b2i * 64 + ((vl + b2i) & 63)] = okv ? (a2[j] + bi) / 0.75 : -INFINITY;
    xs[b3i * 64 + ((vl + b3i) & 63)] = okv ? (a3[j] + bi) / 0.75 : -INFINITY;
  }
  __syncthreads();
  if (tid < 64) {
    int b = tid;
    double tv[5]; int ti[5];
#pragma unroll
    for (int p = 0; p < 5; ++p) { tv[p] = -INFINITY; ti[p] = INT_MAX; }
    for (int vl2 = 0; vl2 < 64; ++vl2)
      ins5(xs[b * 64 + ((vl2 + b) & 63)], vbase + vl2, tv, ti);
#pragma unroll
    for (int r = 0; r < 5; ++r) {
      candV[(size_t)b * NCAND + blockIdx.x * 5 + r] = tv[r];
      candI[(size_t)b * NCAND + blockIdx.x * 5 + r] = ti[r];
    }
  }
}

// -------- refine + finalize: approx top-16 -> exact f64 logits -> top5/gumbel/probs --------
__global__ __launch_bounds__(256) void k_rfin(const double* __restrict__ candV, const int* __restrict__ candI,
                                              const float* __restrict__ W, const float* __restrict__ fcb,
                                              const double* __restrict__ h1T,
                                              const double* __restrict__ gum, int t,
                                              const float* __restrict__ embed,
                                              float* __restrict__ out, double* __restrict__ xt0) {
  __shared__ float sv[NCAND];
  __shared__ int   si[NCAND];
  __shared__ double exS[NREF];
  __shared__ float wvv[4]; __shared__ int wvi[4]; __shared__ int wvs[4];
  int b = blockIdx.x, tid = threadIdx.x;
  int l = tid & 63, wvd = tid >> 6;
  for (int e = tid; e < NCAND; e += 256) {
    sv[e] = (float)candV[(size_t)b * NCAND + e];
    si[e] = candI[(size_t)b * NCAND + e];
  }
  __syncthreads();
  int cidx[NREF];
#pragma unroll
  for (int r = 0; r < NREF; ++r) {
    float bv = -INFINITY; int bi = INT_MAX, bs = 0;
    for (int e = tid; e < NCAND; e += 256) {
      float v = sv[e]; int i2 = si[e];
      if (v > bv || (v == bv && i2 < bi)) { bv = v; bi = i2; bs = e; }
    }
#pragma unroll
    for (int off = 1; off < 64; off <<= 1) {
      float ov = __shfl_xor(bv, off, 64);
      int oi = __shfl_xor(bi, off, 64);
      int os = __shfl_xor(bs, off, 64);
      if (ov > bv || (ov == bv && oi < bi)) { bv = ov; bi = oi; bs = os; }
    }
    if (l == 0) { wvv[wvd] = bv; wvi[wvd] = bi; wvs[wvd] = bs; }
    __syncthreads();
    float fv = wvv[0]; int fi = wvi[0], fs = wvs[0];
#pragma unroll
    for (int q = 1; q < 4; ++q) {
      float ov = wvv[q]; int oi = wvi[q], os = wvs[q];
      if (ov > fv || (ov == fv && oi < fi)) { fv = ov; fi = oi; fs = os; }
    }
    cidx[r] = fi;
    __syncthreads();
    if (tid == 0) sv[fs] = -INFINITY;
    __syncthreads();
  }
  // exact dots: wave wvd handles candidates wvd, wvd+4, wvd+8, wvd+12 (no block barriers)
#pragma unroll
  for (int rr = 0; rr < 4; ++rr) {
    int c = wvd + rr * 4;
    int vc = cidx[c];
    double p = 0.0;
#pragma unroll
    for (int i = 0; i < 16; ++i) {
      int k = i * 64 + l;
      p = fma((double)W[(size_t)k * VSZ + vc], h1T[(size_t)k * 64 + b], p);
    }
#pragma unroll
    for (int off = 1; off < 64; off <<= 1) p += __shfl_xor(p, off, 64);
    if (l == 0) exS[c] = (p + (double)fcb[vc]) / 0.75;
  }
  __syncthreads();
  double tv[5]; int ti[5];
#pragma unroll
  for (int p = 0; p < 5; ++p) { tv[p] = -INFINITY; ti[p] = INT_MAX; }
#pragma unroll
  for (int c = 0; c < NREF; ++c) ins5(exS[c], cidx[c], tv, ti);
  const double* g = gum + (size_t)t * 320 + b * 5;
  double bestv = tv[0] + g[0]; int best = 0;
#pragma unroll
  for (int k2 = 1; k2 < 5; ++k2) { double vv2 = tv[k2] + g[k2]; if (vv2 > bestv) { bestv = vv2; best = k2; } }
  int nxt = ti[best];
  if (tid == 0) {
    out[b * TSZ + t] = (float)nxt;
    double m = tv[0];
    double exx[5]; double s = 0.0;
#pragma unroll
    for (int k2 = 0; k2 < 5; ++k2) { exx[k2] = exp(tv[k2] - m); s += exx[k2]; }
    float* po = out + BSZ * TSZ + ((size_t)b * TSZ + t) * 5;
#pragma unroll
    for (int k2 = 0; k2 < 5; ++k2) po[k2] = (float)(exx[k2] / s);
  }
  xt0[(size_t)tid * 64 + b] = (double)embed[(size_t)nxt * ESZ + tid];
}

// -------- initial embedding of SOS --------
__global__ __launch_bounds__(256) void k_emb0(const float* __restrict__ embed, const int* __restrict__ sos,
                                              double* __restrict__ xt0) {
  int idx = blockIdx.x * 256 + threadIdx.x;
  int b = idx & 63, k = idx >> 6;
  xt0[(size_t)k * 64 + b] = (double)embed[(size_t)sos[0] * ESZ + k];
}

extern "C" void kernel_launch(void* const* d_in, const int* in_sizes, int n_in,
                              void* d_out, int out_size, void* d_ws, size_t ws_size,
                              hipStream_t stream) {
  const float* hours = (const float*)d_in[0];
  const float* tp_w1 = (const float*)d_in[1];
  const float* tp_b1 = (const float*)d_in[2];
  const float* tp_w2 = (const float*)d_in[3];
  const float* tp_b2 = (const float*)d_in[4];
  const float* embed = (const float*)d_in[5];
  const float* w_ih0 = (const float*)d_in[6];
  const float* w_hh0 = (const float*)d_in[7];
  const float* b0    = (const float*)d_in[8];
  const float* w_ih1 = (const float*)d_in[9];
  const float* w_hh1 = (const float*)d_in[10];
  const float* b1    = (const float*)d_in[11];
  const float* fc_w  = (const float*)d_in[12];
  const float* fc_b  = (const float*)d_in[13];
  const int*   sos   = (const int*)d_in[14];
  float* out = (float*)d_out;

  char* w = (char*)d_ws;
  double* part = (double*)w;  w += (size_t)NSLOT * 64 * GC * 8;   // 27.3 MB lstm partials
  double* xt0  = (double*)w;  w += (size_t)ESZ * 64 * 8;
  double* h0T  = (double*)w;  w += (size_t)HSZ * 64 * 8;
  double* h1T  = (double*)w;  w += (size_t)HSZ * 64 * 8;
  double* c0   = (double*)w;  w += (size_t)BSZ * HSZ * 8;
  double* c1   = (double*)w;  w += (size_t)BSZ * HSZ * 8;
  double* tp1T = (double*)w;  w += (size_t)HSZ * 64 * 8;
  double* gum  = (double*)w;  w += (size_t)TSZ * 320 * 8;
  double* candV = (double*)w; w += (size_t)BSZ * NCAND * 8;       // 2.01 MB, b-major
  int*    candI = (int*)w;    w += (size_t)BSZ * NCAND * 4;       // 1.01 MB
  int*    fbuf  = (int*)w;    w += 64;                            // [0]=f64 conv, [2]=bf16 ok
  u16*    xhg   = (u16*)w;    w += (size_t)HSZ * 64 * 2;          // 128 KB bf16 h1 (chunk layout)
  u16*    whT   = (u16*)w;    w += (size_t)VSZ * 1024 * 2;        // 102.9 MB transposed bf16 fc_w
  size_t need = (size_t)(w - (char*)d_ws);
  int useBF = (ws_size >= need) ? 1 : 0;

  k_probe<<<dim3(1), dim3(64), 0, stream>>>(fbuf);
  k_rng<<<dim3(100), dim3(256), 0, stream>>>(gum);
  k_time1<<<dim3(256), dim3(256), 0, stream>>>(hours, tp_w1, tp_b1, tp1T);
  k_gemm_simple<<<dim3(16, 8), dim3(256), 0, stream>>>(tp1T, tp_w2, 1024, 8, part);
  k_t2r<<<dim3(16, 64), dim3(256), 0, stream>>>(part, tp_b2, h0T, c0, h1T, c1);
  k_emb0<<<dim3(64), dim3(256), 0, stream>>>(embed, sos, xt0);
  if (useBF)
    k_wconv<<<dim3(786, 16), dim3(256), 0, stream>>>(fc_w, whT);

  double* part9 = part + (size_t)9 * 64 * GC;
  for (int t = 0; t < TSZ; ++t) {
    // A: slot 0 = xt0*w_ih0 (K=256), slots 1-4 = h0*w_hh0, slots 5-8 = h1*w_hh1
    k_lstm_mfma<<<dim3(64, 9), dim3(256), 0, stream>>>(xt0, w_ih0, h0T, w_hh0, h1T, w_hh1, 1, 5, part, fbuf);
    // layer-0 cell: slots 0..4
    k_cell<<<dim3(4, 64), dim3(256), 0, stream>>>(part, 0, 5, b0, c0, h0T, 0, xhg);
    // B: slices 0-3 = h0n*w_ih1 -> slots 9..12
    k_lstm_mfma<<<dim3(64, 4), dim3(256), 0, stream>>>(h0T, w_ih1, h0T, w_ih1, h0T, w_ih1, 4, 4, part9, fbuf);
    // layer-1 cell: slots 5..12 = h1*w_hh1 (5-8) + h0n*w_ih1 (9-12)
    k_cell<<<dim3(4, 64), dim3(256), 0, stream>>>(part, 5, 8, b1, c1, h1T, 1, xhg);
    if (useBF)
      k_fcbf<<<dim3(NFCB), dim3(256), 0, stream>>>(xhg, whT, fc_b, candV, candI, fbuf);
    else
      k_fcf64<<<dim3(NFCB), dim3(256), 0, stream>>>(h1T, fc_w, fc_b, candV, candI, fbuf);
    k_rfin<<<dim3(64), dim3(256), 0, stream>>>(candV, candI, fc_w, fc_b, h1T, gum, t, embed, out, xt0);
  }
}